// Round 8
// baseline (384.644 us; speedup 1.0000x reference)
//
#include <hip/hip_runtime.h>

// B=4, S=2048, D=512, fp32 in/out. threshold 1.45e-1.
// Pipeline (Hermitian-packed D-FFTs: one 512-pt FFT serves TWO rows):
//  k1 : u=dyt_a(x); XfH = FFT_D(u)          (wave-register FFT, bitrev bins, half2 storage)
//  k2 : per column-PAIR: in-place radix-4 2048-pt S-FFT (fp32 LDS, fp16 global),
//       spectral op, exact inverse, *rtw/S. Twiddles from a 682-entry LDS table.
//  k3 : per TWO ROW-PAIRS per wave (R25): Hermitian combine, x1, dyt_b; q,k
//       Parseval-packed; v packed inverse FFT. All three FFTs run as DUAL
//       interleaved chains (wfft512d) -- R21's +latency experiment showed
//       kernel time ~= sum of per-wave chain time (barrier convoy: all waves
//       drain DS together, compute together, never overlap). ILP inside the
//       wave fills the DS-wait gaps with the sibling chain's VALU. Grid 512,
//       launch_bounds(256,2): 2 waves/SIMD x 2 chains = same 4 chains/SIMD,
//       2x per-wave ILP, ~90 live VGPRs < 256 budget.
//  g1 : scores = q@k^T
//  smtr: full softmax per row written in place as bf16 P + v->vT transpose.
//  g2 : attn = P@vT, split-K x2, fp16 partials.
//  k5 : row-pair packed dyt_f + spectral filter (sums TWO fp16 partials)
// k3 theory ledger: DS-throughput x (R21), chain+VALU harmful (R21),
// spills x (R24), convoy/ILP <- this round.

typedef __attribute__((ext_vector_type(8))) __bf16 bf16x8;
typedef __attribute__((ext_vector_type(4))) float floatx4;
typedef __attribute__((ext_vector_type(8))) _Float16 halfx8;
typedef __attribute__((ext_vector_type(8))) unsigned short ushortx8;
typedef __attribute__((ext_vector_type(2))) _Float16 half2v;   // 4B packed complex (re,im)
typedef __attribute__((ext_vector_type(4))) _Float16 half4v;   // 8B = two packed complex

__device__ __forceinline__ unsigned short f2bf(float x) {
    unsigned u = __float_as_uint(x);
    u = (u + 0x7fffu + ((u >> 16) & 1u)) >> 16;
    return (unsigned short)u;
}

__device__ __forceinline__ float dyt_tanh(float x) {
    float e = __expf(2.0f * x);
    return 1.0f - 2.0f / (e + 1.0f);
}

__device__ __forceinline__ void async_load16(const unsigned short* g, unsigned short* l) {
    __builtin_amdgcn_global_load_lds(
        (const __attribute__((address_space(1))) unsigned int*)g,
        (__attribute__((address_space(3))) unsigned int*)l, 16, 0, 0);
}

// ---------- wave-level 512-pt FFT (8 pts/lane) ----------
__device__ __forceinline__ void wtw512(float (&tc)[12], float (&ts)[12], int lane) {
    const float w = -6.28318530717958647692f / 512.0f;
#pragma unroll
    for (int j = 0; j < 4; j++) __sincosf(w * (float)(j * 64 + lane), &ts[j], &tc[j]);
#pragma unroll
    for (int j = 0; j < 2; j++) __sincosf(w * (float)(2 * (j * 64 + lane)), &ts[4 + j], &tc[4 + j]);
    __sincosf(w * (float)(4 * lane), &ts[6], &tc[6]);
    __sincosf(w * (float)(8 * (lane & 31)), &ts[7], &tc[7]);
    __sincosf(w * (float)(16 * (lane & 15)), &ts[8], &tc[8]);
    __sincosf(w * (float)(32 * (lane & 7)), &ts[9], &tc[9]);
    __sincosf(w * (float)(64 * (lane & 3)), &ts[10], &tc[10]);
    __sincosf(w * (float)(128 * (lane & 1)), &ts[11], &tc[11]);
}

template <bool INV>
__device__ __forceinline__ void wfft512(float (&re)[8], float (&im)[8],
                                        const float (&tc)[12], const float (&ts)[12], int lane) {
    if (!INV) {
#pragma unroll
        for (int j = 0; j < 4; j++) {
            float ur = re[j], ui = im[j], vr = re[j + 4], vi = im[j + 4];
            re[j] = ur + vr; im[j] = ui + vi;
            float dr = ur - vr, di = ui - vi;
            re[j + 4] = dr * tc[j] - di * ts[j];
            im[j + 4] = dr * ts[j] + di * tc[j];
        }
#pragma unroll
        for (int g = 0; g < 8; g += 4)
#pragma unroll
            for (int jj = 0; jj < 2; jj++) {
                int j = g + jj;
                float ur = re[j], ui = im[j], vr = re[j + 2], vi = im[j + 2];
                re[j] = ur + vr; im[j] = ui + vi;
                float dr = ur - vr, di = ui - vi;
                re[j + 2] = dr * tc[4 + jj] - di * ts[4 + jj];
                im[j + 2] = dr * ts[4 + jj] + di * tc[4 + jj];
            }
#pragma unroll
        for (int j = 0; j < 8; j += 2) {
            float ur = re[j], ui = im[j], vr = re[j + 1], vi = im[j + 1];
            re[j] = ur + vr; im[j] = ui + vi;
            float dr = ur - vr, di = ui - vi;
            re[j + 1] = dr * tc[6] - di * ts[6];
            im[j + 1] = dr * ts[6] + di * tc[6];
        }
#pragma unroll
        for (int st = 0; st < 6; st++) {
            int h = 32 >> st;
            bool hi = (lane & h) != 0;
            float c = (st < 5) ? tc[7 + st] : 1.0f;
            float s = (st < 5) ? ts[7 + st] : 0.0f;
#pragma unroll
            for (int j = 0; j < 8; j++) {
                float orr = __shfl_xor(re[j], h, 64);
                float oii = __shfl_xor(im[j], h, 64);
                float dr = orr - re[j], di = oii - im[j];
                float sr = re[j] + orr, si = im[j] + oii;
                re[j] = hi ? (dr * c - di * s) : sr;
                im[j] = hi ? (dr * s + di * c) : si;
            }
        }
    } else {
#pragma unroll
        for (int st = 5; st >= 0; st--) {
            int h = 32 >> st;
            bool hi = (lane & h) != 0;
            float c = (st < 5) ? tc[7 + st] : 1.0f;
            float s = (st < 5) ? ts[7 + st] : 0.0f;
#pragma unroll
            for (int j = 0; j < 8; j++) {
                float zr = re[j], zi = im[j];
                float vr = zr * c + zi * s;
                float vi = zi * c - zr * s;
                float mr = hi ? vr : zr;
                float mi = hi ? vi : zi;
                float orr = __shfl_xor(mr, h, 64);
                float oii = __shfl_xor(mi, h, 64);
                re[j] = hi ? (orr - vr) : (zr + orr);
                im[j] = hi ? (oii - vi) : (zi + oii);
            }
        }
#pragma unroll
        for (int j = 0; j < 8; j += 2) {
            float vr = re[j + 1] * tc[6] + im[j + 1] * ts[6];
            float vi = im[j + 1] * tc[6] - re[j + 1] * ts[6];
            re[j + 1] = re[j] - vr; im[j + 1] = im[j] - vi;
            re[j] += vr; im[j] += vi;
        }
#pragma unroll
        for (int g = 0; g < 8; g += 4)
#pragma unroll
            for (int jj = 0; jj < 2; jj++) {
                int j = g + jj;
                float vr = re[j + 2] * tc[4 + jj] + im[j + 2] * ts[4 + jj];
                float vi = im[j + 2] * tc[4 + jj] - re[j + 2] * ts[4 + jj];
                re[j + 2] = re[j] - vr; im[j + 2] = im[j] - vi;
                re[j] += vr; im[j] += vi;
            }
#pragma unroll
        for (int j = 0; j < 4; j++) {
            float vr = re[j + 4] * tc[j] + im[j + 4] * ts[j];
            float vi = im[j + 4] * tc[j] - re[j + 4] * ts[j];
            re[j + 4] = re[j] - vr; im[j + 4] = im[j] - vi;
            re[j] += vr; im[j] += vi;
        }
    }
}

// ---------- DUAL interleaved 512-pt FFT: two independent chains per wave ----------
template <bool INV>
__device__ __forceinline__ void wfft512d(float (&reA)[8], float (&imA)[8],
                                         float (&reB)[8], float (&imB)[8],
                                         const float (&tc)[12], const float (&ts)[12], int lane) {
    if (!INV) {
#pragma unroll
        for (int j = 0; j < 4; j++) {
            {
                float ur = reA[j], ui = imA[j], vr = reA[j + 4], vi = imA[j + 4];
                reA[j] = ur + vr; imA[j] = ui + vi;
                float dr = ur - vr, di = ui - vi;
                reA[j + 4] = dr * tc[j] - di * ts[j];
                imA[j + 4] = dr * ts[j] + di * tc[j];
            }
            {
                float ur = reB[j], ui = imB[j], vr = reB[j + 4], vi = imB[j + 4];
                reB[j] = ur + vr; imB[j] = ui + vi;
                float dr = ur - vr, di = ui - vi;
                reB[j + 4] = dr * tc[j] - di * ts[j];
                imB[j + 4] = dr * ts[j] + di * tc[j];
            }
        }
#pragma unroll
        for (int g = 0; g < 8; g += 4)
#pragma unroll
            for (int jj = 0; jj < 2; jj++) {
                int j = g + jj;
                {
                    float ur = reA[j], ui = imA[j], vr = reA[j + 2], vi = imA[j + 2];
                    reA[j] = ur + vr; imA[j] = ui + vi;
                    float dr = ur - vr, di = ui - vi;
                    reA[j + 2] = dr * tc[4 + jj] - di * ts[4 + jj];
                    imA[j + 2] = dr * ts[4 + jj] + di * tc[4 + jj];
                }
                {
                    float ur = reB[j], ui = imB[j], vr = reB[j + 2], vi = imB[j + 2];
                    reB[j] = ur + vr; imB[j] = ui + vi;
                    float dr = ur - vr, di = ui - vi;
                    reB[j + 2] = dr * tc[4 + jj] - di * ts[4 + jj];
                    imB[j + 2] = dr * ts[4 + jj] + di * tc[4 + jj];
                }
            }
#pragma unroll
        for (int j = 0; j < 8; j += 2) {
            {
                float ur = reA[j], ui = imA[j], vr = reA[j + 1], vi = imA[j + 1];
                reA[j] = ur + vr; imA[j] = ui + vi;
                float dr = ur - vr, di = ui - vi;
                reA[j + 1] = dr * tc[6] - di * ts[6];
                imA[j + 1] = dr * ts[6] + di * tc[6];
            }
            {
                float ur = reB[j], ui = imB[j], vr = reB[j + 1], vi = imB[j + 1];
                reB[j] = ur + vr; imB[j] = ui + vi;
                float dr = ur - vr, di = ui - vi;
                reB[j + 1] = dr * tc[6] - di * ts[6];
                imB[j + 1] = dr * ts[6] + di * tc[6];
            }
        }
#pragma unroll
        for (int st = 0; st < 6; st++) {
            int h = 32 >> st;
            bool hi = (lane & h) != 0;
            float c = (st < 5) ? tc[7 + st] : 1.0f;
            float s = (st < 5) ? ts[7 + st] : 0.0f;
#pragma unroll
            for (int j = 0; j < 8; j++) {
                float oAr = __shfl_xor(reA[j], h, 64);
                float oAi = __shfl_xor(imA[j], h, 64);
                float oBr = __shfl_xor(reB[j], h, 64);
                float oBi = __shfl_xor(imB[j], h, 64);
                {
                    float dr = oAr - reA[j], di = oAi - imA[j];
                    float sr = reA[j] + oAr, si = imA[j] + oAi;
                    reA[j] = hi ? (dr * c - di * s) : sr;
                    imA[j] = hi ? (dr * s + di * c) : si;
                }
                {
                    float dr = oBr - reB[j], di = oBi - imB[j];
                    float sr = reB[j] + oBr, si = imB[j] + oBi;
                    reB[j] = hi ? (dr * c - di * s) : sr;
                    imB[j] = hi ? (dr * s + di * c) : si;
                }
            }
        }
    } else {
#pragma unroll
        for (int st = 5; st >= 0; st--) {
            int h = 32 >> st;
            bool hi = (lane & h) != 0;
            float c = (st < 5) ? tc[7 + st] : 1.0f;
            float s = (st < 5) ? ts[7 + st] : 0.0f;
#pragma unroll
            for (int j = 0; j < 8; j++) {
                float zAr = reA[j], zAi = imA[j];
                float vAr = zAr * c + zAi * s;
                float vAi = zAi * c - zAr * s;
                float mAr = hi ? vAr : zAr;
                float mAi = hi ? vAi : zAi;
                float zBr = reB[j], zBi = imB[j];
                float vBr = zBr * c + zBi * s;
                float vBi = zBi * c - zBr * s;
                float mBr = hi ? vBr : zBr;
                float mBi = hi ? vBi : zBi;
                float oAr = __shfl_xor(mAr, h, 64);
                float oAi = __shfl_xor(mAi, h, 64);
                float oBr = __shfl_xor(mBr, h, 64);
                float oBi = __shfl_xor(mBi, h, 64);
                reA[j] = hi ? (oAr - vAr) : (zAr + oAr);
                imA[j] = hi ? (oAi - vAi) : (zAi + oAi);
                reB[j] = hi ? (oBr - vBr) : (zBr + oBr);
                imB[j] = hi ? (oBi - vBi) : (zBi + oBi);
            }
        }
#pragma unroll
        for (int j = 0; j < 8; j += 2) {
            {
                float vr = reA[j + 1] * tc[6] + imA[j + 1] * ts[6];
                float vi = imA[j + 1] * tc[6] - reA[j + 1] * ts[6];
                reA[j + 1] = reA[j] - vr; imA[j + 1] = imA[j] - vi;
                reA[j] += vr; imA[j] += vi;
            }
            {
                float vr = reB[j + 1] * tc[6] + imB[j + 1] * ts[6];
                float vi = imB[j + 1] * tc[6] - reB[j + 1] * ts[6];
                reB[j + 1] = reB[j] - vr; imB[j + 1] = imB[j] - vi;
                reB[j] += vr; imB[j] += vi;
            }
        }
#pragma unroll
        for (int g = 0; g < 8; g += 4)
#pragma unroll
            for (int jj = 0; jj < 2; jj++) {
                int j = g + jj;
                {
                    float vr = reA[j + 2] * tc[4 + jj] + imA[j + 2] * ts[4 + jj];
                    float vi = imA[j + 2] * tc[4 + jj] - reA[j + 2] * ts[4 + jj];
                    reA[j + 2] = reA[j] - vr; imA[j + 2] = imA[j] - vi;
                    reA[j] += vr; imA[j] += vi;
                }
                {
                    float vr = reB[j + 2] * tc[4 + jj] + imB[j + 2] * ts[4 + jj];
                    float vi = imB[j + 2] * tc[4 + jj] - reB[j + 2] * ts[4 + jj];
                    reB[j + 2] = reB[j] - vr; imB[j + 2] = imB[j] - vi;
                    reB[j] += vr; imB[j] += vi;
                }
            }
#pragma unroll
        for (int j = 0; j < 4; j++) {
            {
                float vr = reA[j + 4] * tc[j] + imA[j + 4] * ts[j];
                float vi = imA[j + 4] * tc[j] - reA[j + 4] * ts[j];
                reA[j + 4] = reA[j] - vr; imA[j + 4] = imA[j] - vi;
                reA[j] += vr; imA[j] += vi;
            }
            {
                float vr = reB[j + 4] * tc[j] + imB[j + 4] * ts[j];
                float vi = imB[j + 4] * tc[j] - reB[j + 4] * ts[j];
                reB[j + 4] = reB[j] - vr; imB[j + 4] = imB[j] - vi;
                reB[j] += vr; imB[j] += vi;
            }
        }
    }
}

// ---------------- k1 : dyt_a + forward D-FFT (half2 output) ----------------
__global__ __launch_bounds__(256, 4) void k1_dyt_fftd(
        const float* __restrict__ x,
        const float* __restrict__ alpha, const float* __restrict__ w, const float* __restrict__ bia,
        half2v* __restrict__ xf) {
    int tid = threadIdx.x, lane = tid & 63, wv = tid >> 6;
    size_t row = (size_t)blockIdx.x * 4 + wv;
    float tc[12], ts[12];
    wtw512(tc, ts, lane);
    float re[8], im[8];
    float a = alpha[0];
    const float* xr = x + row * 512;
#pragma unroll
    for (int j = 0; j < 8; j++) {
        int d = j * 64 + lane;
        re[j] = dyt_tanh(a * xr[d]) * w[d] + bia[d];
        im[j] = 0.f;
    }
    wfft512<false>(re, im, tc, ts, lane);
#pragma unroll
    for (int j = 0; j < 8; j++) {
        int d = j * 64 + lane;
        xf[row * 512 + d] = (half2v){(_Float16)re[j], (_Float16)im[j]};
    }
}

// ---------------- k2 : in-place radix-4 2048-pt S-FFT, 2 cols/block ----------------
__device__ __forceinline__ int pidx4(int i) { return i + (i >> 3); }

// Both fwd and inv read the SAME table entry (c,s) = sincos(-2*pi*pos/(4h));
// inv applies the conjugate internally (u = y*(c - i*s)).
__device__ __forceinline__ void r4_fwd(float4* X, int t, int h, const half2v* tw) {
    int pos = t & (h - 1);
    int i = ((t & ~(h - 1)) << 2) | pos;
    int i0 = pidx4(i), i1 = pidx4(i + h), i2 = pidx4(i + 2 * h), i3 = pidx4(i + 3 * h);
    float4 a0 = X[i0], a1 = X[i1], a2 = X[i2], a3 = X[i3];
    half2v wv = tw[pos];
    float c1 = (float)wv.x, s1 = (float)wv.y;
    float c2 = c1 * c1 - s1 * s1, s2 = 2.f * c1 * s1;
    float c3 = c2 * c1 - s2 * s1, s3 = s2 * c1 + c2 * s1;
    float4 o0, o1, o2, o3;
    {
        float t0r = a0.x + a2.x, t0i = a0.y + a2.y, t1r = a0.x - a2.x, t1i = a0.y - a2.y;
        float t2r = a1.x + a3.x, t2i = a1.y + a3.y, t3r = a1.x - a3.x, t3i = a1.y - a3.y;
        o0.x = t0r + t2r; o0.y = t0i + t2i;
        float b1r = t1r + t3i, b1i = t1i - t3r;
        float b2r = t0r - t2r, b2i = t0i - t2i;
        float b3r = t1r - t3i, b3i = t1i + t3r;
        o1.x = b1r * c1 - b1i * s1; o1.y = b1r * s1 + b1i * c1;
        o2.x = b2r * c2 - b2i * s2; o2.y = b2r * s2 + b2i * c2;
        o3.x = b3r * c3 - b3i * s3; o3.y = b3r * s3 + b3i * c3;
    }
    {
        float t0r = a0.z + a2.z, t0i = a0.w + a2.w, t1r = a0.z - a2.z, t1i = a0.w - a2.w;
        float t2r = a1.z + a3.z, t2i = a1.w + a3.w, t3r = a1.z - a3.z, t3i = a1.w - a3.w;
        o0.z = t0r + t2r; o0.w = t0i + t2i;
        float b1r = t1r + t3i, b1i = t1i - t3r;
        float b2r = t0r - t2r, b2i = t0i - t2i;
        float b3r = t1r - t3i, b3i = t1i + t3r;
        o1.z = b1r * c1 - b1i * s1; o1.w = b1r * s1 + b1i * c1;
        o2.z = b2r * c2 - b2i * s2; o2.w = b2r * s2 + b2i * c2;
        o3.z = b3r * c3 - b3i * s3; o3.w = b3r * s3 + b3i * c3;
    }
    X[i0] = o0; X[i1] = o1; X[i2] = o2; X[i3] = o3;
}

__device__ __forceinline__ void r4_inv(float4* X, int t, int h, const half2v* tw) {
    int pos = t & (h - 1);
    int i = ((t & ~(h - 1)) << 2) | pos;
    int i0 = pidx4(i), i1 = pidx4(i + h), i2 = pidx4(i + 2 * h), i3 = pidx4(i + 3 * h);
    float4 y0 = X[i0], y1 = X[i1], y2 = X[i2], y3 = X[i3];
    half2v wv = tw[pos];
    float c1 = (float)wv.x, s1 = (float)wv.y;
    float c2 = c1 * c1 - s1 * s1, s2 = 2.f * c1 * s1;
    float c3 = c2 * c1 - s2 * s1, s3 = s2 * c1 + c2 * s1;
    float4 o0, o1, o2, o3;
    {
        float u1r = y1.x * c1 + y1.y * s1, u1i = y1.y * c1 - y1.x * s1;
        float u2r = y2.x * c2 + y2.y * s2, u2i = y2.y * c2 - y2.x * s2;
        float u3r = y3.x * c3 + y3.y * s3, u3i = y3.y * c3 - y3.x * s3;
        float s0r = y0.x + u2r, s0i = y0.y + u2i;
        float s1r = y0.x - u2r, s1i = y0.y - u2i;
        float s2r = u1r + u3r, s2i = u1i + u3i;
        float s3r = u1r - u3r, s3i = u1i - u3i;
        o0.x = s0r + s2r; o0.y = s0i + s2i;
        o2.x = s0r - s2r; o2.y = s0i - s2i;
        o1.x = s1r - s3i; o1.y = s1i + s3r;
        o3.x = s1r + s3i; o3.y = s1i - s3r;
    }
    {
        float u1r = y1.z * c1 + y1.w * s1, u1i = y1.w * c1 - y1.z * s1;
        float u2r = y2.z * c2 + y2.w * s2, u2i = y2.w * c2 - y2.z * s2;
        float u3r = y3.z * c3 + y3.w * s3, u3i = y3.w * c3 - y3.z * s3;
        float s0r = y0.z + u2r, s0i = y0.w + u2i;
        float s1r = y0.z - u2r, s1i = y0.w - u2i;
        float s2r = u1r + u3r, s2i = u1i + u3i;
        float s3r = u1r - u3r, s3i = u1i - u3i;
        o0.z = s0r + s2r; o0.w = s0i + s2i;
        o2.z = s0r - s2r; o2.w = s0i - s2i;
        o1.z = s1r - s3i; o1.w = s1i + s3r;
        o3.z = s1r + s3i; o3.w = s1i - s3r;
    }
    X[i0] = o0; X[i1] = o1; X[i2] = o2; X[i3] = o3;
}

__global__ __launch_bounds__(512) void k2_sfft(
        half2v* __restrict__ xf,
        const float* __restrict__ qr, const float* __restrict__ qi,
        const float* __restrict__ kr, const float* __restrict__ ki,
        const float* __restrict__ vr, const float* __restrict__ vi,
        const float* __restrict__ rtr, const float* __restrict__ rti) {
    __shared__ float4 buf[2304];
    __shared__ half2v twd[682];   // fwd twiddles: h=512@0, 128@512, 32@640, 8@672, 2@680
    int t = threadIdx.x;
    int g = blockIdx.x;
    int xcd = g & 7, r = g >> 3;
    int pp = xcd * 32 + (r & 31);
    int b = r >> 5;
    int p0 = pp * 2;
    half4v* colh = (half4v*)(xf + (size_t)b * 2048 * 512 + p0);

    // cooperative twiddle-table fill (2 passes over 512 threads)
    for (int i = t; i < 682; i += 512) {
        int h, off;
        if (i < 512)      { h = 512; off = 0; }
        else if (i < 640) { h = 128; off = 512; }
        else if (i < 672) { h = 32;  off = 640; }
        else if (i < 680) { h = 8;   off = 672; }
        else              { h = 2;   off = 680; }
        int pos = i - off;
        float s, c;
        __sincosf(-6.28318530717958647692f * (float)pos / (float)(4 * h), &s, &c);
        twd[i] = (half2v){(_Float16)c, (_Float16)s};
    }

#pragma unroll
    for (int c = 0; c < 4; c++) {
        int s = t + 512 * c;
        half4v h = colh[(size_t)s * 256];
        buf[pidx4(s)] = make_float4((float)h.x, (float)h.y, (float)h.z, (float)h.w);
    }
    __syncthreads(); r4_fwd(buf, t, 512, twd);
    __syncthreads(); r4_fwd(buf, t, 128, twd + 512);
    __syncthreads(); r4_fwd(buf, t, 32, twd + 640);
    __syncthreads(); r4_fwd(buf, t, 8, twd + 672);
    __syncthreads(); r4_fwd(buf, t, 2, twd + 680);
    __syncthreads();
#pragma unroll
    for (int c = 0; c < 2; c++) {
        int pr = t + 512 * c;
        int ia = pidx4(2 * pr), ib = pidx4(2 * pr + 1);
        float4 a = buf[ia], bb = buf[ib];
        buf[ia] = make_float4(a.x + bb.x, a.y + bb.y, a.z + bb.z, a.w + bb.w);
        buf[ib] = make_float4(a.x - bb.x, a.y - bb.y, a.z - bb.z, a.w - bb.w);
    }
    __syncthreads();

    int f0 = __brev((unsigned)p0) >> 23;
    int f1 = __brev((unsigned)(p0 + 1)) >> 23;
    float qw0r = qr[f0], qw0i = qi[f0], kw0r = kr[f0], kw0i = ki[f0], vw0r = vr[f0], vw0i = vi[f0];
    float qw1r = qr[f1], qw1i = qi[f1], kw1r = kr[f1], kw1i = ki[f1], vw1r = vr[f1], vw1i = vi[f1];
#pragma unroll
    for (int c = 0; c < 4; c++) {
        int idx = pidx4(t + 512 * c);
        float4 y = buf[idx];
        {
            float yr = y.x, yi = y.y;
            float qre = yr * qw0r - yi * qw0i, qim = yr * qw0i + yi * qw0r;
            float kre = yr * kw0r - yi * kw0i + 1e-12f, kim = yr * kw0i + yi * kw0r;
            float vre = yr * vw0r - yi * vw0i, vim = yr * vw0i + yi * vw0r;
            float inv = 1.0f / (kre * kre + kim * kim);
            float dre = (qre * kre + qim * kim) * inv;
            float dim = (qim * kre - qre * kim) * inv;
            y.x = dre * vre - dim * vim;
            y.y = dre * vim + dim * vre;
        }
        {
            float yr = y.z, yi = y.w;
            float qre = yr * qw1r - yi * qw1i, qim = yr * qw1i + yi * qw1r;
            float kre = yr * kw1r - yi * kw1i + 1e-12f, kim = yr * kw1i + yi * kw1r;
            float vre = yr * vw1r - yi * vw1i, vim = yr * vw1i + yi * vw1r;
            float inv = 1.0f / (kre * kre + kim * kim);
            float dre = (qre * kre + qim * kim) * inv;
            float dim = (qim * kre - qre * kim) * inv;
            y.z = dre * vre - dim * vim;
            y.w = dre * vim + dim * vre;
        }
        buf[idx] = y;
    }

    __syncthreads();
#pragma unroll
    for (int c = 0; c < 2; c++) {
        int pr = t + 512 * c;
        int ia = pidx4(2 * pr), ib = pidx4(2 * pr + 1);
        float4 a = buf[ia], bb = buf[ib];
        buf[ia] = make_float4(a.x + bb.x, a.y + bb.y, a.z + bb.z, a.w + bb.w);
        buf[ib] = make_float4(a.x - bb.x, a.y - bb.y, a.z - bb.z, a.w - bb.w);
    }
    __syncthreads(); r4_inv(buf, t, 2, twd + 680);
    __syncthreads(); r4_inv(buf, t, 8, twd + 672);
    __syncthreads(); r4_inv(buf, t, 32, twd + 640);
    __syncthreads(); r4_inv(buf, t, 128, twd + 512);
    __syncthreads(); r4_inv(buf, t, 512, twd);
    __syncthreads();

    const float sc = 1.0f / 2048.0f;
    float r0r = rtr[f0] * sc, r0i = rti[f0] * sc;
    float r1r = rtr[f1] * sc, r1i = rti[f1] * sc;
#pragma unroll
    for (int c = 0; c < 4; c++) {
        int s = t + 512 * c;
        float4 z = buf[pidx4(s)];
        float ox = z.x * r0r - z.y * r0i, oy = z.x * r0i + z.y * r0r;
        float oz = z.z * r1r - z.w * r1i, ow = z.z * r1i + z.w * r1r;
        colh[(size_t)s * 256] = (half4v){(_Float16)ox, (_Float16)oy, (_Float16)oz, (_Float16)ow};
    }
}

// ---------------- k3 : TWO row-pairs per wave, dual interleaved FFT chains ----------------
__global__ __launch_bounds__(256, 2) void k3_mid(
        const half2v* __restrict__ xf,
        const float* __restrict__ x,
        const float* __restrict__ alpha, const float* __restrict__ w, const float* __restrict__ bia,
        const float* __restrict__ qr, const float* __restrict__ qi,
        const float* __restrict__ kr, const float* __restrict__ ki,
        const float* __restrict__ vr, const float* __restrict__ vi,
        float* __restrict__ x1,
        unsigned short* __restrict__ qb, unsigned short* __restrict__ kb, unsigned short* __restrict__ vb) {
    __shared__ __align__(16) char smem[4 * 1024 * 8];  // 32KB (layout unchanged)
    int tid = threadIdx.x, lane = tid & 63, wv = tid >> 6;
    float2* zb = (float2*)(smem + wv * 8192);          // phase1: wave-private 8KB, reused A then B
    float* wbs = (float*)smem;                          // [6][512]=12KB (after combine)
    float2* zf = (float2*)(smem + 12288 + wv * 4096);  // phase2: wave-private 4KB, reused A then B
    size_t wid = (size_t)blockIdx.x * 4 + wv;           // [0, 2048)
    size_t r1A = wid * 4, r2A = r1A + 1, r1B = r1A + 2, r2B = r1A + 3;
    float tc[12], ts[12];
    wtw512(tc, ts, lane);

    float xaA[8], xbA[8], xaB[8], xbB[8];
    float reA[8], imA[8], reB[8], imB[8];
    // ---- combine pair A (zb pass 1) ----
#pragma unroll
    for (int j = 0; j < 8; j++) {
        int d = j * 64 + lane;
        half2v h1 = xf[r1A * 512 + d];
        half2v h2 = xf[r2A * 512 + d];
        zb[d]       = make_float2((float)h1.x, (float)h1.y);
        zb[512 + d] = make_float2((float)h2.x, (float)h2.y);
        xaA[j] = x[r1A * 512 + d];
        xbA[j] = x[r2A * 512 + d];
    }
#pragma unroll
    for (int j = 0; j < 8; j++) {
        int d = j * 64 + lane;
        int fd = __brev((unsigned)d) >> 23;
        int dp = __brev((unsigned)((512 - fd) & 511)) >> 23;
        float2 z1 = zb[d], z1p = zb[dp];
        float2 z2 = zb[512 + d], z2p = zb[512 + dp];
        float h1r = 0.5f * (z1.x + z1p.x), h1i = 0.5f * (z1.y - z1p.y);
        float h2r = 0.5f * (z2.x + z2p.x), h2i = 0.5f * (z2.y - z2p.y);
        reA[j] = h1r - h2i;
        imA[j] = h1i + h2r;
    }
    // ---- combine pair B (zb pass 2; same-wave DS ordering keeps RAW/WAR safe) ----
#pragma unroll
    for (int j = 0; j < 8; j++) {
        int d = j * 64 + lane;
        half2v h1 = xf[r1B * 512 + d];
        half2v h2 = xf[r2B * 512 + d];
        zb[d]       = make_float2((float)h1.x, (float)h1.y);
        zb[512 + d] = make_float2((float)h2.x, (float)h2.y);
        xaB[j] = x[r1B * 512 + d];
        xbB[j] = x[r2B * 512 + d];
    }
#pragma unroll
    for (int j = 0; j < 8; j++) {
        int d = j * 64 + lane;
        int fd = __brev((unsigned)d) >> 23;
        int dp = __brev((unsigned)((512 - fd) & 511)) >> 23;
        float2 z1 = zb[d], z1p = zb[dp];
        float2 z2 = zb[512 + d], z2p = zb[512 + dp];
        float h1r = 0.5f * (z1.x + z1p.x), h1i = 0.5f * (z1.y - z1p.y);
        float h2r = 0.5f * (z2.x + z2p.x), h2i = 0.5f * (z2.y - z2p.y);
        reB[j] = h1r - h2i;
        imB[j] = h1i + h2r;
    }
    __syncthreads();
    for (int idx = tid; idx < 512; idx += 256) {
        int f = __brev((unsigned)idx) >> 23;
        int gg = (512 - f) & 511;
        float aa = (f == 0 || f == 256) ? 0.04419417382415922f : 0.0625f;
        float ah = aa * 0.5f;
        const float s5 = 0.5f * (1.0f / 512.0f);
        wbs[0 * 512 + idx] = ah * (qr[f] + qr[gg]); wbs[1 * 512 + idx] = ah * (qi[f] - qi[gg]);
        wbs[2 * 512 + idx] = ah * (kr[f] + kr[gg]); wbs[3 * 512 + idx] = ah * (ki[f] - ki[gg]);
        wbs[4 * 512 + idx] = s5 * (vr[f] + vr[gg]); wbs[5 * 512 + idx] = s5 * (vi[f] - vi[gg]);
    }

    wfft512d<true>(reA, imA, reB, imB, tc, ts, lane);
    float a = alpha[0];
    float greA[8], gimA[8], greB[8], gimB[8];
#pragma unroll
    for (int j = 0; j < 8; j++) {
        int d = j * 64 + lane;
        float v1 = reA[j] * (1.0f / 512.0f) + xaA[j];
        float v2 = imA[j] * (1.0f / 512.0f) + xbA[j];
        x1[r1A * 512 + d] = v1;
        x1[r2A * 512 + d] = v2;
        greA[j] = dyt_tanh(a * v1) * w[d] + bia[d];
        gimA[j] = dyt_tanh(a * v2) * w[d] + bia[d];
    }
#pragma unroll
    for (int j = 0; j < 8; j++) {
        int d = j * 64 + lane;
        float v1 = reB[j] * (1.0f / 512.0f) + xaB[j];
        float v2 = imB[j] * (1.0f / 512.0f) + xbB[j];
        x1[r1B * 512 + d] = v1;
        x1[r2B * 512 + d] = v2;
        greB[j] = dyt_tanh(a * v1) * w[d] + bia[d];
        gimB[j] = dyt_tanh(a * v2) * w[d] + bia[d];
    }
    wfft512d<false>(greA, gimA, greB, gimB, tc, ts, lane);
    __syncthreads();

    bool odd = (lane & 1) != 0;
    float pvrA[8], pviA[8], pvrB[8], pviB[8];
    // ---- pack pair A (zf pass 1) ----
#pragma unroll
    for (int j = 0; j < 8; j++)
        zf[j * 64 + lane] = make_float2(greA[j], gimA[j]);
#pragma unroll
    for (int j = 0; j < 8; j++) {
        int i = j * 64 + lane;
        float wr0 = wbs[4 * 512 + i], wi0 = wbs[5 * 512 + i];
        pvrA[j] = greA[j] * wr0 - gimA[j] * wi0;
        pviA[j] = greA[j] * wi0 + gimA[j] * wr0;
    }
#pragma unroll
    for (int j = 0; j < 8; j++) {
        int d = j * 64 + lane;
        int fd = __brev((unsigned)d) >> 23;
        int dp = __brev((unsigned)((512 - fd) & 511)) >> 23;
        float2 Zp = zf[dp];
        float zr = greA[j], zi = gimA[j];
        float A1r = 0.5f * (zr + Zp.x), A1i = 0.5f * (zi - Zp.y);
        float A2r = 0.5f * (zi + Zp.y), A2i = 0.5f * (Zp.x - zr);
        float wr0 = wbs[0 * 512 + d], wi0 = wbs[1 * 512 + d];
        float Q1r = A1r * wr0 - A1i * wi0, Q1i = A1r * wi0 + A1i * wr0;
        float Q2r = A2r * wr0 - A2i * wi0, Q2i = A2r * wi0 + A2i * wr0;
        qb[r1A * 512 + d] = f2bf(odd ? -Q1i : Q1r);
        qb[r2A * 512 + d] = f2bf(odd ? -Q2i : Q2r);
        float wr1 = wbs[2 * 512 + d], wi1 = wbs[3 * 512 + d];
        float K1r = A1r * wr1 - A1i * wi1, K1i = A1r * wi1 + A1i * wr1;
        float K2r = A2r * wr1 - A2i * wi1, K2i = A2r * wi1 + A2i * wr1;
        kb[r1A * 512 + d] = f2bf(odd ? -K1i : K1r);
        kb[r2A * 512 + d] = f2bf(odd ? -K2i : K2r);
    }
    // ---- pack pair B (zf pass 2) ----
#pragma unroll
    for (int j = 0; j < 8; j++)
        zf[j * 64 + lane] = make_float2(greB[j], gimB[j]);
#pragma unroll
    for (int j = 0; j < 8; j++) {
        int i = j * 64 + lane;
        float wr0 = wbs[4 * 512 + i], wi0 = wbs[5 * 512 + i];
        pvrB[j] = greB[j] * wr0 - gimB[j] * wi0;
        pviB[j] = greB[j] * wi0 + gimB[j] * wr0;
    }
#pragma unroll
    for (int j = 0; j < 8; j++) {
        int d = j * 64 + lane;
        int fd = __brev((unsigned)d) >> 23;
        int dp = __brev((unsigned)((512 - fd) & 511)) >> 23;
        float2 Zp = zf[dp];
        float zr = greB[j], zi = gimB[j];
        float A1r = 0.5f * (zr + Zp.x), A1i = 0.5f * (zi - Zp.y);
        float A2r = 0.5f * (zi + Zp.y), A2i = 0.5f * (Zp.x - zr);
        float wr0 = wbs[0 * 512 + d], wi0 = wbs[1 * 512 + d];
        float Q1r = A1r * wr0 - A1i * wi0, Q1i = A1r * wi0 + A1i * wr0;
        float Q2r = A2r * wr0 - A2i * wi0, Q2i = A2r * wi0 + A2i * wr0;
        qb[r1B * 512 + d] = f2bf(odd ? -Q1i : Q1r);
        qb[r2B * 512 + d] = f2bf(odd ? -Q2i : Q2r);
        float wr1 = wbs[2 * 512 + d], wi1 = wbs[3 * 512 + d];
        float K1r = A1r * wr1 - A1i * wi1, K1i = A1r * wi1 + A1i * wr1;
        float K2r = A2r * wr1 - A2i * wi1, K2i = A2r * wi1 + A2i * wr1;
        kb[r1B * 512 + d] = f2bf(odd ? -K1i : K1r);
        kb[r2B * 512 + d] = f2bf(odd ? -K2i : K2r);
    }

    wfft512d<true>(pvrA, pviA, pvrB, pviB, tc, ts, lane);
#pragma unroll
    for (int j = 0; j < 8; j++) {
        int d = j * 64 + lane;
        vb[r1A * 512 + d] = f2bf(pvrA[j]);
        vb[r2A * 512 + d] = f2bf(pviA[j]);
        vb[r1B * 512 + d] = f2bf(pvrB[j]);
        vb[r2B * 512 + d] = f2bf(pviB[j]);
    }
}

// ---------------- unified bt-GEMM (BK=64, global_load_lds, XOR-swizzled LDS) ----------------
__global__ __launch_bounds__(256) void gemm_bt(
        const unsigned short* __restrict__ A, const unsigned short* __restrict__ Bt,
        void* __restrict__ C, int M, int N, int Ks, int kseg, float scale, int out_half) {
    int tilesM = M >> 7, tilesN = N >> 7;
    int perBatch = tilesM * tilesN;
    int l = blockIdx.x;
    int seg = blockIdx.y;
    int s = l & 7, t = l >> 3;
    int cnt = perBatch >> 3;
    int bz = t / cnt;
    int u = t - bz * cnt;
    int pn = tilesN >> 1, pm = tilesM >> 2;
    int n0 = ((s & 1) * pn + (u % pn)) << 7;
    int m0 = ((s >> 1) * pm + (u / pn)) << 7;
    int kbase = seg * kseg;

    const unsigned short* Ab = A + (size_t)bz * M * Ks;
    const unsigned short* Bb = Bt + (size_t)bz * N * Ks;
    __shared__ __align__(16) unsigned short smem[2 * 128 * 64];
    unsigned short* As = smem;
    unsigned short* Bs = smem + 128 * 64;
    int tid = threadIdx.x;
    int wave = tid >> 6, lane = tid & 63;
    int wm = (wave >> 1) * 64, wn = (wave & 1) * 64;
    int lrow = lane & 15, lq = lane >> 4;
    floatx4 acc[4][4];
#pragma unroll
    for (int i = 0; i < 4; i++)
#pragma unroll
        for (int j = 0; j < 4; j++)
            acc[i][j] = (floatx4){0.f, 0.f, 0.f, 0.f};

    int lr = lane >> 3;
    int lcs = lane & 7;
    for (int k0 = kbase; k0 < kbase + kseg; k0 += 64) {
        __syncthreads();
#pragma unroll
        for (int i = 0; i < 4; i++) {
            int c = wave * 4 + i;
            int r = c * 8 + lr;
            int gcol = ((lcs ^ (r & 7)) << 3);
            async_load16(Ab + (size_t)(m0 + r) * Ks + k0 + gcol, As + c * 512);
            async_load16(Bb + (size_t)(n0 + r) * Ks + k0 + gcol, Bs + c * 512);
        }
        __syncthreads();
        bf16x8 a0[4], a1[4], b0[4], b1[4];
#pragma unroll
        for (int mi = 0; mi < 4; mi++) {
            int r = wm + mi * 16 + lrow;
            a0[mi] = *(const bf16x8*)(As + r * 64 + ((lq ^ (r & 7)) << 3));
            a1[mi] = *(const bf16x8*)(As + r * 64 + (((lq + 4) ^ (r & 7)) << 3));
        }
#pragma unroll
        for (int ni = 0; ni < 4; ni++) {
            int r = wn + ni * 16 + lrow;
            b0[ni] = *(const bf16x8*)(Bs + r * 64 + ((lq ^ (r & 7)) << 3));
            b1[ni] = *(const bf16x8*)(Bs + r * 64 + (((lq + 4) ^ (r & 7)) << 3));
        }
#pragma unroll
        for (int mi = 0; mi < 4; mi++)
#pragma unroll
            for (int ni = 0; ni < 4; ni++) {
                acc[mi][ni] = __builtin_amdgcn_mfma_f32_16x16x32_bf16(a0[mi], b0[ni], acc[mi][ni], 0, 0, 0);
                acc[mi][ni] = __builtin_amdgcn_mfma_f32_16x16x32_bf16(a1[mi], b1[ni], acc[mi][ni], 0, 0, 0);
            }
    }
    size_t cbase = ((size_t)seg * 4 + bz) * (size_t)M * N;
    int lr0 = (wave >> 1) * 16 + lq * 4;
    for (int mi = 0; mi < 4; mi++) {
        __syncthreads();
        if (out_half) {
            _Float16* Cs = (_Float16*)smem;
            for (int ni = 0; ni < 4; ni++)
                for (int r = 0; r < 4; r++)
                    Cs[(lr0 + r) * 128 + wn + ni * 16 + lrow] = (_Float16)(acc[mi][ni][r] * scale);
            __syncthreads();
            for (int h = 0; h < 2; h++) {
                int chunk = tid + h * 256;
                int rl = chunk >> 4, cb = (chunk & 15) * 16;
                int grow = m0 + mi * 16 + (rl & 15) + (rl >> 4) * 64;
                *(uint4*)((char*)C + (cbase + (size_t)grow * N + n0) * 2 + cb) =
                    *(const uint4*)((const char*)Cs + rl * 256 + cb);
            }
        } else {
            float* Cs = (float*)smem;
            for (int ni = 0; ni < 4; ni++)
                for (int r = 0; r < 4; r++)
                    Cs[(lr0 + r) * 128 + wn + ni * 16 + lrow] = acc[mi][ni][r] * scale;
            __syncthreads();
            for (int h = 0; h < 4; h++) {
                int chunk = tid + h * 256;
                int rl = chunk >> 5, cb = (chunk & 31) * 16;
                int grow = m0 + mi * 16 + (rl & 15) + (rl >> 4) * 64;
                *(uint4*)((char*)C + (cbase + (size_t)grow * N + n0) * 4 + cb) =
                    *(const uint4*)((const char*)Cs + rl * 512 + cb);
            }
        }
    }
}

// ---------------- softmax (in-place bf16 P) + v->vT transpose, one grid ----------------
__global__ __launch_bounds__(256) void sm_tr(
        const _Float16* __restrict__ Sc, unsigned short* __restrict__ P,
        const unsigned short* __restrict__ vb, unsigned short* __restrict__ vT) {
    __shared__ __align__(16) char lds[64 * 65 * 2];  // transpose tile; softmax uses first 16B
    if (blockIdx.x < 8192) {
        float* red = (float*)lds;
        int tid = threadIdx.x;
        size_t row = blockIdx.x;
        halfx8 hv = *(const halfx8*)(Sc + row * 2048 + tid * 8);
        float v[8];
#pragma unroll
        for (int j = 0; j < 8; j++) v[j] = (float)hv[j];
        float mx = v[0];
#pragma unroll
        for (int j = 1; j < 8; j++) mx = fmaxf(mx, v[j]);
        for (int off = 32; off >= 1; off >>= 1) mx = fmaxf(mx, __shfl_xor(mx, off));
        int wv = tid >> 6;
        if ((tid & 63) == 0) red[wv] = mx;
        __syncthreads();
        mx = fmaxf(fmaxf(red[0], red[1]), fmaxf(red[2], red[3]));
        float e[8], sum = 0.f;
#pragma unroll
        for (int j = 0; j < 8; j++) { e[j] = __expf(v[j] - mx); sum += e[j]; }
        for (int off = 32; off >= 1; off >>= 1) sum += __shfl_xor(sum, off);
        __syncthreads();
        if ((tid & 63) == 0) red[wv] = sum;
        __syncthreads();
        float inv = 1.0f / (red[0] + red[1] + red[2] + red[3]);
        ushortx8 o;
#pragma unroll
        for (int j = 0; j < 8; j++) o[j] = f2bf(e[j] * inv);
        *(ushortx8*)(P + row * 2048 + tid * 8) = o;
    } else {
        unsigned short (*tile)[65] = (unsigned short (*)[65])lds;
        int id = blockIdx.x - 8192;           // 1024 transpose blocks: (32, 8, 4)
        int sx = id & 31, dy = (id >> 5) & 7, bz = id >> 8;
        int s0 = sx * 64, d0 = dy * 64;
        int tx = threadIdx.x & 63, ty = threadIdx.x >> 6;
        for (int j = 0; j < 16; j++) {
            int s = ty + j * 4;
            tile[s][tx] = vb[((size_t)bz * 2048 + s0 + s) * 512 + d0 + tx];
        }
        __syncthreads();
        for (int j = 0; j < 16; j++) {
            int d = ty + j * 4;
            vT[((size_t)bz * 512 + d0 + d) * 2048 + s0 + tx] = tile[tx][d];
        }
    }
}

// ---------------- k5 : row-pair residual + dyt_f + spectral filter ----------------
// Sums TWO fp16 split-K partials.
__global__ __launch_bounds__(256, 4) void k5_ffn(
        const _Float16* __restrict__ attn0, const _Float16* __restrict__ attn1,
        const float* __restrict__ x1,
        const float* __restrict__ alpha, const float* __restrict__ w, const float* __restrict__ bia,
        const float* __restrict__ br, const float* __restrict__ bi,
        float* __restrict__ out) {
    __shared__ float wbs[2][512];
    int tid = threadIdx.x, lane = tid & 63, wv = tid >> 6;
    size_t pr = (size_t)blockIdx.x * 4 + wv;
    size_t r1 = pr * 2, r2 = r1 + 1;
    for (int idx = tid; idx < 512; idx += 256) {
        int f = __brev((unsigned)idx) >> 23;
        int gg = (512 - f) & 511;
        wbs[0][idx] = 0.5f * (br[f] + br[gg]) * (1.0f / 512.0f);
        wbs[1][idx] = 0.5f * (bi[f] - bi[gg]) * (1.0f / 512.0f);
    }
    float tc[12], ts[12];
    wtw512(tc, ts, lane);
    float a = alpha[0];
    float re[8], im[8], x2a[8], x2b[8];
#pragma unroll
    for (int j = 0; j < 8; j++) {
        int d = j * 64 + lane;
        float v1 = (float)attn0[r1 * 512 + d] + (float)attn1[r1 * 512 + d] + x1[r1 * 512 + d];
        float v2 = (float)attn0[r2 * 512 + d] + (float)attn1[r2 * 512 + d] + x1[r2 * 512 + d];
        x2a[j] = v1; x2b[j] = v2;
        re[j] = dyt_tanh(a * v1) * w[d] + bia[d];
        im[j] = dyt_tanh(a * v2) * w[d] + bia[d];
    }
    wfft512<false>(re, im, tc, ts, lane);
    __syncthreads();
#pragma unroll
    for (int j = 0; j < 8; j++) {
        int i = j * 64 + lane;
        float wr0 = wbs[0][i], wi0 = wbs[1][i];
        float rr = re[j], ii = im[j];
        re[j] = rr * wr0 - ii * wi0;
        im[j] = rr * wi0 + ii * wr0;
    }
    wfft512<true>(re, im, tc, ts, lane);
#pragma unroll
    for (int j = 0; j < 8; j++) {
        int d = j * 64 + lane;
        out[r1 * 512 + d] = re[j] + x2a[j];
        out[r2 * 512 + d] = im[j] + x2b[j];
    }
}

extern "C" void kernel_launch(void* const* d_in, const int* in_sizes, int n_in,
                              void* d_out, int out_size, void* d_ws, size_t ws_size,
                              hipStream_t stream) {
    const float* x      = (const float*)d_in[0];
    const float* a_qr   = (const float*)d_in[1];
    const float* a_kr   = (const float*)d_in[2];
    const float* a_vr   = (const float*)d_in[3];
    const float* a_rtr  = (const float*)d_in[4];
    const float* b_qr   = (const float*)d_in[5];
    const float* b_kr   = (const float*)d_in[6];
    const float* b_vr   = (const float*)d_in[7];
    /* f_ar = d_in[8] unused (dead gelu branch) */
    const float* f_br   = (const float*)d_in[9];
    const float* a_qi   = (const float*)d_in[10];
    const float* a_ki   = (const float*)d_in[11];
    const float* a_vi   = (const float*)d_in[12];
    const float* a_rti  = (const float*)d_in[13];
    const float* b_qi   = (const float*)d_in[14];
    const float* b_ki   = (const float*)d_in[15];
    const float* b_vi   = (const float*)d_in[16];
    /* f_ai = d_in[17] unused */
    const float* f_bi   = (const float*)d_in[18];
    /* f_bias = d_in[19] unused (dead gelu branch) */
    const float* dyta_alpha = (const float*)d_in[20];
    const float* dyta_w     = (const float*)d_in[21];
    const float* dyta_b     = (const float*)d_in[22];
    const float* dytb_alpha = (const float*)d_in[23];
    const float* dytb_w     = (const float*)d_in[24];
    const float* dytb_b     = (const float*)d_in[25];
    const float* dytf_alpha = (const float*)d_in[26];
    const float* dytf_w     = (const float*)d_in[27];
    const float* dytf_b     = (const float*)d_in[28];
    (void)in_sizes; (void)n_in; (void)out_size; (void)ws_size;

    char* ws = (char*)d_ws;
    const size_t MB = 1024 * 1024;
    half2v* xfH = (half2v*)(ws + 0 * MB);           // 16MB packed fp16 complex
    float* x1   = (float*)(ws + 32 * MB);           // 16MB
    unsigned short* qb = (unsigned short*)(ws + 48 * MB);  // 8MB
    unsigned short* kb = (unsigned short*)(ws + 56 * MB);  // 8MB
    unsigned short* vb = (unsigned short*)(ws + 64 * MB);  // 8MB
    unsigned short* vT = (unsigned short*)(ws + 72 * MB);  // 8MB
    _Float16* scores   = (_Float16*)(ws + 0 * MB);  // 32MB, overlays dead xfH
    unsigned short* Pb = (unsigned short*)(ws + 0 * MB);   // bf16 P, in place over scores
    _Float16* attnP    = (_Float16*)(ws + 81 * MB); // 16MB: two 8MB fp16 K-split partials
    float* outp = (float*)d_out;

    k1_dyt_fftd<<<2048, 256, 0, stream>>>(x, dyta_alpha, dyta_w, dyta_b, xfH);
    k2_sfft<<<1024, 512, 0, stream>>>(xfH, a_qr, a_qi, a_kr, a_ki, a_vr, a_vi, a_rtr, a_rti);
    k3_mid<<<512, 256, 0, stream>>>(xfH, x, dytb_alpha, dytb_w, dytb_b,
                                    b_qr, b_qi, b_kr, b_ki, b_vr, b_vi, x1, qb, kb, vb);
    gemm_bt<<<1024, 256, 0, stream>>>(qb, kb, scores, 2048, 2048, 512, 512,
                                      0.04419417382415922f, 1);
    sm_tr<<<9216, 256, 0, stream>>>(scores, Pb, vb, vT);
    gemm_bt<<<dim3(256, 2), 256, 0, stream>>>(Pb, vT, attnP, 2048, 512, 2048, 1024,
                                              1.0f, 1);
    k5_ffn<<<1024, 256, 0, stream>>>(attnP, attnP + (size_t)4 * 2048 * 512, x1,
                                     dytf_alpha, dytf_w, dytf_b, f_br, f_bi, outp);
}

// Round 9
// 277.904 us; speedup vs baseline: 1.3841x; 1.3841x over previous
//
#include <hip/hip_runtime.h>

// B=4, S=2048, D=512, fp32 in/out. threshold 1.45e-1.
// Pipeline (Hermitian-packed D-FFTs: one 512-pt FFT serves TWO rows):
//  k1 : u=dyt_a(x); XfH = FFT_D(u)          (wave-register FFT, bitrev bins, half2 storage)
//  k2 : per column-PAIR: in-place radix-4 2048-pt S-FFT (fp32 LDS, fp16 global),
//       spectral op, exact inverse, *rtw/S. Twiddles from a 682-entry LDS table.
//  k3 : per ROW-PAIR: Hermitian combine, x1, dyt_b; q,k Parseval-packed in the
//       frequency domain (no inverse FFTs); v packed inverse FFT.
//  g1 : scores = q@k^T
//  smtr: full softmax per row written in place as bf16 P + v->vT transpose.
//  g2 : attn = P@vT, split-K x2, fp16 partials.
//  k5 : row-pair packed dyt_f + spectral filter (sums TWO fp16 partials)
// R26: exact revert to R24 (281.93us best). R25's dual-chain k3 regressed
// 100us: at 2 waves/SIMD per-wave issue rate rose 6.25%->7% only -- the
// interleave produced ~no ILP; k3's stall-hiding is pure TLP, best at
// 1 chain/wave x 4 waves/SIMD. k3 theory ledger (all refuted): DS-throughput
// (R21), +VALU-on-chain (R21, harmful), spills (R24), convoy/ILP (R25).
// Remaining k3 headroom requires 2-wave-per-FFT redesign (cross-wave LDS
// stages) -- expected negative given DS pipe is the stall source.

typedef __attribute__((ext_vector_type(8))) __bf16 bf16x8;
typedef __attribute__((ext_vector_type(4))) float floatx4;
typedef __attribute__((ext_vector_type(8))) _Float16 halfx8;
typedef __attribute__((ext_vector_type(8))) unsigned short ushortx8;
typedef __attribute__((ext_vector_type(2))) _Float16 half2v;   // 4B packed complex (re,im)
typedef __attribute__((ext_vector_type(4))) _Float16 half4v;   // 8B = two packed complex

__device__ __forceinline__ unsigned short f2bf(float x) {
    unsigned u = __float_as_uint(x);
    u = (u + 0x7fffu + ((u >> 16) & 1u)) >> 16;
    return (unsigned short)u;
}

__device__ __forceinline__ float dyt_tanh(float x) {
    float e = __expf(2.0f * x);
    return 1.0f - 2.0f / (e + 1.0f);
}

__device__ __forceinline__ void async_load16(const unsigned short* g, unsigned short* l) {
    __builtin_amdgcn_global_load_lds(
        (const __attribute__((address_space(1))) unsigned int*)g,
        (__attribute__((address_space(3))) unsigned int*)l, 16, 0, 0);
}

// ---------- wave-level 512-pt FFT (8 pts/lane) ----------
__device__ __forceinline__ void wtw512(float (&tc)[12], float (&ts)[12], int lane) {
    const float w = -6.28318530717958647692f / 512.0f;
#pragma unroll
    for (int j = 0; j < 4; j++) __sincosf(w * (float)(j * 64 + lane), &ts[j], &tc[j]);
#pragma unroll
    for (int j = 0; j < 2; j++) __sincosf(w * (float)(2 * (j * 64 + lane)), &ts[4 + j], &tc[4 + j]);
    __sincosf(w * (float)(4 * lane), &ts[6], &tc[6]);
    __sincosf(w * (float)(8 * (lane & 31)), &ts[7], &tc[7]);
    __sincosf(w * (float)(16 * (lane & 15)), &ts[8], &tc[8]);
    __sincosf(w * (float)(32 * (lane & 7)), &ts[9], &tc[9]);
    __sincosf(w * (float)(64 * (lane & 3)), &ts[10], &tc[10]);
    __sincosf(w * (float)(128 * (lane & 1)), &ts[11], &tc[11]);
}

template <bool INV>
__device__ __forceinline__ void wfft512(float (&re)[8], float (&im)[8],
                                        const float (&tc)[12], const float (&ts)[12], int lane) {
    if (!INV) {
#pragma unroll
        for (int j = 0; j < 4; j++) {
            float ur = re[j], ui = im[j], vr = re[j + 4], vi = im[j + 4];
            re[j] = ur + vr; im[j] = ui + vi;
            float dr = ur - vr, di = ui - vi;
            re[j + 4] = dr * tc[j] - di * ts[j];
            im[j + 4] = dr * ts[j] + di * tc[j];
        }
#pragma unroll
        for (int g = 0; g < 8; g += 4)
#pragma unroll
            for (int jj = 0; jj < 2; jj++) {
                int j = g + jj;
                float ur = re[j], ui = im[j], vr = re[j + 2], vi = im[j + 2];
                re[j] = ur + vr; im[j] = ui + vi;
                float dr = ur - vr, di = ui - vi;
                re[j + 2] = dr * tc[4 + jj] - di * ts[4 + jj];
                im[j + 2] = dr * ts[4 + jj] + di * tc[4 + jj];
            }
#pragma unroll
        for (int j = 0; j < 8; j += 2) {
            float ur = re[j], ui = im[j], vr = re[j + 1], vi = im[j + 1];
            re[j] = ur + vr; im[j] = ui + vi;
            float dr = ur - vr, di = ui - vi;
            re[j + 1] = dr * tc[6] - di * ts[6];
            im[j + 1] = dr * ts[6] + di * tc[6];
        }
#pragma unroll
        for (int st = 0; st < 6; st++) {
            int h = 32 >> st;
            bool hi = (lane & h) != 0;
            float c = (st < 5) ? tc[7 + st] : 1.0f;
            float s = (st < 5) ? ts[7 + st] : 0.0f;
#pragma unroll
            for (int j = 0; j < 8; j++) {
                float orr = __shfl_xor(re[j], h, 64);
                float oii = __shfl_xor(im[j], h, 64);
                float dr = orr - re[j], di = oii - im[j];
                float sr = re[j] + orr, si = im[j] + oii;
                re[j] = hi ? (dr * c - di * s) : sr;
                im[j] = hi ? (dr * s + di * c) : si;
            }
        }
    } else {
#pragma unroll
        for (int st = 5; st >= 0; st--) {
            int h = 32 >> st;
            bool hi = (lane & h) != 0;
            float c = (st < 5) ? tc[7 + st] : 1.0f;
            float s = (st < 5) ? ts[7 + st] : 0.0f;
#pragma unroll
            for (int j = 0; j < 8; j++) {
                float zr = re[j], zi = im[j];
                float vr = zr * c + zi * s;
                float vi = zi * c - zr * s;
                float mr = hi ? vr : zr;
                float mi = hi ? vi : zi;
                float orr = __shfl_xor(mr, h, 64);
                float oii = __shfl_xor(mi, h, 64);
                re[j] = hi ? (orr - vr) : (zr + orr);
                im[j] = hi ? (oii - vi) : (zi + oii);
            }
        }
#pragma unroll
        for (int j = 0; j < 8; j += 2) {
            float vr = re[j + 1] * tc[6] + im[j + 1] * ts[6];
            float vi = im[j + 1] * tc[6] - re[j + 1] * ts[6];
            re[j + 1] = re[j] - vr; im[j + 1] = im[j] - vi;
            re[j] += vr; im[j] += vi;
        }
#pragma unroll
        for (int g = 0; g < 8; g += 4)
#pragma unroll
            for (int jj = 0; jj < 2; jj++) {
                int j = g + jj;
                float vr = re[j + 2] * tc[4 + jj] + im[j + 2] * ts[4 + jj];
                float vi = im[j + 2] * tc[4 + jj] - re[j + 2] * ts[4 + jj];
                re[j + 2] = re[j] - vr; im[j + 2] = im[j] - vi;
                re[j] += vr; im[j] += vi;
            }
#pragma unroll
        for (int j = 0; j < 4; j++) {
            float vr = re[j + 4] * tc[j] + im[j + 4] * ts[j];
            float vi = im[j + 4] * tc[j] - re[j + 4] * ts[j];
            re[j + 4] = re[j] - vr; im[j + 4] = im[j] - vi;
            re[j] += vr; im[j] += vi;
        }
    }
}

// ---------------- k1 : dyt_a + forward D-FFT (half2 output) ----------------
__global__ __launch_bounds__(256, 4) void k1_dyt_fftd(
        const float* __restrict__ x,
        const float* __restrict__ alpha, const float* __restrict__ w, const float* __restrict__ bia,
        half2v* __restrict__ xf) {
    int tid = threadIdx.x, lane = tid & 63, wv = tid >> 6;
    size_t row = (size_t)blockIdx.x * 4 + wv;
    float tc[12], ts[12];
    wtw512(tc, ts, lane);
    float re[8], im[8];
    float a = alpha[0];
    const float* xr = x + row * 512;
#pragma unroll
    for (int j = 0; j < 8; j++) {
        int d = j * 64 + lane;
        re[j] = dyt_tanh(a * xr[d]) * w[d] + bia[d];
        im[j] = 0.f;
    }
    wfft512<false>(re, im, tc, ts, lane);
#pragma unroll
    for (int j = 0; j < 8; j++) {
        int d = j * 64 + lane;
        xf[row * 512 + d] = (half2v){(_Float16)re[j], (_Float16)im[j]};
    }
}

// ---------------- k2 : in-place radix-4 2048-pt S-FFT, 2 cols/block ----------------
__device__ __forceinline__ int pidx4(int i) { return i + (i >> 3); }

// Both fwd and inv read the SAME table entry (c,s) = sincos(-2*pi*pos/(4h));
// inv applies the conjugate internally (u = y*(c - i*s)).
__device__ __forceinline__ void r4_fwd(float4* X, int t, int h, const half2v* tw) {
    int pos = t & (h - 1);
    int i = ((t & ~(h - 1)) << 2) | pos;
    int i0 = pidx4(i), i1 = pidx4(i + h), i2 = pidx4(i + 2 * h), i3 = pidx4(i + 3 * h);
    float4 a0 = X[i0], a1 = X[i1], a2 = X[i2], a3 = X[i3];
    half2v wv = tw[pos];
    float c1 = (float)wv.x, s1 = (float)wv.y;
    float c2 = c1 * c1 - s1 * s1, s2 = 2.f * c1 * s1;
    float c3 = c2 * c1 - s2 * s1, s3 = s2 * c1 + c2 * s1;
    float4 o0, o1, o2, o3;
    {
        float t0r = a0.x + a2.x, t0i = a0.y + a2.y, t1r = a0.x - a2.x, t1i = a0.y - a2.y;
        float t2r = a1.x + a3.x, t2i = a1.y + a3.y, t3r = a1.x - a3.x, t3i = a1.y - a3.y;
        o0.x = t0r + t2r; o0.y = t0i + t2i;
        float b1r = t1r + t3i, b1i = t1i - t3r;
        float b2r = t0r - t2r, b2i = t0i - t2i;
        float b3r = t1r - t3i, b3i = t1i + t3r;
        o1.x = b1r * c1 - b1i * s1; o1.y = b1r * s1 + b1i * c1;
        o2.x = b2r * c2 - b2i * s2; o2.y = b2r * s2 + b2i * c2;
        o3.x = b3r * c3 - b3i * s3; o3.y = b3r * s3 + b3i * c3;
    }
    {
        float t0r = a0.z + a2.z, t0i = a0.w + a2.w, t1r = a0.z - a2.z, t1i = a0.w - a2.w;
        float t2r = a1.z + a3.z, t2i = a1.w + a3.w, t3r = a1.z - a3.z, t3i = a1.w - a3.w;
        o0.z = t0r + t2r; o0.w = t0i + t2i;
        float b1r = t1r + t3i, b1i = t1i - t3r;
        float b2r = t0r - t2r, b2i = t0i - t2i;
        float b3r = t1r - t3i, b3i = t1i + t3r;
        o1.z = b1r * c1 - b1i * s1; o1.w = b1r * s1 + b1i * c1;
        o2.z = b2r * c2 - b2i * s2; o2.w = b2r * s2 + b2i * c2;
        o3.z = b3r * c3 - b3i * s3; o3.w = b3r * s3 + b3i * c3;
    }
    X[i0] = o0; X[i1] = o1; X[i2] = o2; X[i3] = o3;
}

__device__ __forceinline__ void r4_inv(float4* X, int t, int h, const half2v* tw) {
    int pos = t & (h - 1);
    int i = ((t & ~(h - 1)) << 2) | pos;
    int i0 = pidx4(i), i1 = pidx4(i + h), i2 = pidx4(i + 2 * h), i3 = pidx4(i + 3 * h);
    float4 y0 = X[i0], y1 = X[i1], y2 = X[i2], y3 = X[i3];
    half2v wv = tw[pos];
    float c1 = (float)wv.x, s1 = (float)wv.y;
    float c2 = c1 * c1 - s1 * s1, s2 = 2.f * c1 * s1;
    float c3 = c2 * c1 - s2 * s1, s3 = s2 * c1 + c2 * s1;
    float4 o0, o1, o2, o3;
    {
        float u1r = y1.x * c1 + y1.y * s1, u1i = y1.y * c1 - y1.x * s1;
        float u2r = y2.x * c2 + y2.y * s2, u2i = y2.y * c2 - y2.x * s2;
        float u3r = y3.x * c3 + y3.y * s3, u3i = y3.y * c3 - y3.x * s3;
        float s0r = y0.x + u2r, s0i = y0.y + u2i;
        float s1r = y0.x - u2r, s1i = y0.y - u2i;
        float s2r = u1r + u3r, s2i = u1i + u3i;
        float s3r = u1r - u3r, s3i = u1i - u3i;
        o0.x = s0r + s2r; o0.y = s0i + s2i;
        o2.x = s0r - s2r; o2.y = s0i - s2i;
        o1.x = s1r - s3i; o1.y = s1i + s3r;
        o3.x = s1r + s3i; o3.y = s1i - s3r;
    }
    {
        float u1r = y1.z * c1 + y1.w * s1, u1i = y1.w * c1 - y1.z * s1;
        float u2r = y2.z * c2 + y2.w * s2, u2i = y2.w * c2 - y2.z * s2;
        float u3r = y3.z * c3 + y3.w * s3, u3i = y3.w * c3 - y3.z * s3;
        float s0r = y0.z + u2r, s0i = y0.w + u2i;
        float s1r = y0.z - u2r, s1i = y0.w - u2i;
        float s2r = u1r + u3r, s2i = u1i + u3i;
        float s3r = u1r - u3r, s3i = u1i - u3i;
        o0.z = s0r + s2r; o0.w = s0i + s2i;
        o2.z = s0r - s2r; o2.w = s0i - s2i;
        o1.z = s1r - s3i; o1.w = s1i + s3r;
        o3.z = s1r + s3i; o3.w = s1i - s3r;
    }
    X[i0] = o0; X[i1] = o1; X[i2] = o2; X[i3] = o3;
}

__global__ __launch_bounds__(512) void k2_sfft(
        half2v* __restrict__ xf,
        const float* __restrict__ qr, const float* __restrict__ qi,
        const float* __restrict__ kr, const float* __restrict__ ki,
        const float* __restrict__ vr, const float* __restrict__ vi,
        const float* __restrict__ rtr, const float* __restrict__ rti) {
    __shared__ float4 buf[2304];
    __shared__ half2v twd[682];   // fwd twiddles: h=512@0, 128@512, 32@640, 8@672, 2@680
    int t = threadIdx.x;
    int g = blockIdx.x;
    int xcd = g & 7, r = g >> 3;
    int pp = xcd * 32 + (r & 31);
    int b = r >> 5;
    int p0 = pp * 2;
    half4v* colh = (half4v*)(xf + (size_t)b * 2048 * 512 + p0);

    // cooperative twiddle-table fill (2 passes over 512 threads)
    for (int i = t; i < 682; i += 512) {
        int h, off;
        if (i < 512)      { h = 512; off = 0; }
        else if (i < 640) { h = 128; off = 512; }
        else if (i < 672) { h = 32;  off = 640; }
        else if (i < 680) { h = 8;   off = 672; }
        else              { h = 2;   off = 680; }
        int pos = i - off;
        float s, c;
        __sincosf(-6.28318530717958647692f * (float)pos / (float)(4 * h), &s, &c);
        twd[i] = (half2v){(_Float16)c, (_Float16)s};
    }

#pragma unroll
    for (int c = 0; c < 4; c++) {
        int s = t + 512 * c;
        half4v h = colh[(size_t)s * 256];
        buf[pidx4(s)] = make_float4((float)h.x, (float)h.y, (float)h.z, (float)h.w);
    }
    __syncthreads(); r4_fwd(buf, t, 512, twd);
    __syncthreads(); r4_fwd(buf, t, 128, twd + 512);
    __syncthreads(); r4_fwd(buf, t, 32, twd + 640);
    __syncthreads(); r4_fwd(buf, t, 8, twd + 672);
    __syncthreads(); r4_fwd(buf, t, 2, twd + 680);
    __syncthreads();
#pragma unroll
    for (int c = 0; c < 2; c++) {
        int pr = t + 512 * c;
        int ia = pidx4(2 * pr), ib = pidx4(2 * pr + 1);
        float4 a = buf[ia], bb = buf[ib];
        buf[ia] = make_float4(a.x + bb.x, a.y + bb.y, a.z + bb.z, a.w + bb.w);
        buf[ib] = make_float4(a.x - bb.x, a.y - bb.y, a.z - bb.z, a.w - bb.w);
    }
    __syncthreads();

    int f0 = __brev((unsigned)p0) >> 23;
    int f1 = __brev((unsigned)(p0 + 1)) >> 23;
    float qw0r = qr[f0], qw0i = qi[f0], kw0r = kr[f0], kw0i = ki[f0], vw0r = vr[f0], vw0i = vi[f0];
    float qw1r = qr[f1], qw1i = qi[f1], kw1r = kr[f1], kw1i = ki[f1], vw1r = vr[f1], vw1i = vi[f1];
#pragma unroll
    for (int c = 0; c < 4; c++) {
        int idx = pidx4(t + 512 * c);
        float4 y = buf[idx];
        {
            float yr = y.x, yi = y.y;
            float qre = yr * qw0r - yi * qw0i, qim = yr * qw0i + yi * qw0r;
            float kre = yr * kw0r - yi * kw0i + 1e-12f, kim = yr * kw0i + yi * kw0r;
            float vre = yr * vw0r - yi * vw0i, vim = yr * vw0i + yi * vw0r;
            float inv = 1.0f / (kre * kre + kim * kim);
            float dre = (qre * kre + qim * kim) * inv;
            float dim = (qim * kre - qre * kim) * inv;
            y.x = dre * vre - dim * vim;
            y.y = dre * vim + dim * vre;
        }
        {
            float yr = y.z, yi = y.w;
            float qre = yr * qw1r - yi * qw1i, qim = yr * qw1i + yi * qw1r;
            float kre = yr * kw1r - yi * kw1i + 1e-12f, kim = yr * kw1i + yi * kw1r;
            float vre = yr * vw1r - yi * vw1i, vim = yr * vw1i + yi * vw1r;
            float inv = 1.0f / (kre * kre + kim * kim);
            float dre = (qre * kre + qim * kim) * inv;
            float dim = (qim * kre - qre * kim) * inv;
            y.z = dre * vre - dim * vim;
            y.w = dre * vim + dim * vre;
        }
        buf[idx] = y;
    }

    __syncthreads();
#pragma unroll
    for (int c = 0; c < 2; c++) {
        int pr = t + 512 * c;
        int ia = pidx4(2 * pr), ib = pidx4(2 * pr + 1);
        float4 a = buf[ia], bb = buf[ib];
        buf[ia] = make_float4(a.x + bb.x, a.y + bb.y, a.z + bb.z, a.w + bb.w);
        buf[ib] = make_float4(a.x - bb.x, a.y - bb.y, a.z - bb.z, a.w - bb.w);
    }
    __syncthreads(); r4_inv(buf, t, 2, twd + 680);
    __syncthreads(); r4_inv(buf, t, 8, twd + 672);
    __syncthreads(); r4_inv(buf, t, 32, twd + 640);
    __syncthreads(); r4_inv(buf, t, 128, twd + 512);
    __syncthreads(); r4_inv(buf, t, 512, twd);
    __syncthreads();

    const float sc = 1.0f / 2048.0f;
    float r0r = rtr[f0] * sc, r0i = rti[f0] * sc;
    float r1r = rtr[f1] * sc, r1i = rti[f1] * sc;
#pragma unroll
    for (int c = 0; c < 4; c++) {
        int s = t + 512 * c;
        float4 z = buf[pidx4(s)];
        float ox = z.x * r0r - z.y * r0i, oy = z.x * r0i + z.y * r0r;
        float oz = z.z * r1r - z.w * r1i, ow = z.z * r1i + z.w * r1r;
        colh[(size_t)s * 256] = (half4v){(_Float16)ox, (_Float16)oy, (_Float16)oz, (_Float16)ow};
    }
}

// ---------------- k3 : row-pair residual + dyt_b + q/k (Parseval-packed) + v ----------------
__global__ __launch_bounds__(256, 4) void k3_mid(
        const half2v* __restrict__ xf,
        const float* __restrict__ x,
        const float* __restrict__ alpha, const float* __restrict__ w, const float* __restrict__ bia,
        const float* __restrict__ qr, const float* __restrict__ qi,
        const float* __restrict__ kr, const float* __restrict__ ki,
        const float* __restrict__ vr, const float* __restrict__ vi,
        float* __restrict__ x1,
        unsigned short* __restrict__ qb, unsigned short* __restrict__ kb, unsigned short* __restrict__ vb) {
    __shared__ __align__(16) char smem[4 * 1024 * 8];  // 32KB
    int tid = threadIdx.x, lane = tid & 63, wv = tid >> 6;
    float2* zb = (float2*)(smem + wv * 8192);          // phase1: wave-private 8KB
    float* wbs = (float*)smem;                          // [6][512]=12KB (after combine)
    float2* zf = (float2*)(smem + 12288 + wv * 4096);  // phase2: wave-private 4KB
    size_t pr = (size_t)blockIdx.x * 4 + wv;
    size_t r1 = pr * 2, r2 = r1 + 1;
    float tc[12], ts[12];
    wtw512(tc, ts, lane);

    float xa[8], xb2[8];
#pragma unroll
    for (int j = 0; j < 8; j++) {
        int d = j * 64 + lane;
        half2v h1 = xf[r1 * 512 + d];
        half2v h2 = xf[r2 * 512 + d];
        zb[d]       = make_float2((float)h1.x, (float)h1.y);
        zb[512 + d] = make_float2((float)h2.x, (float)h2.y);
        xa[j]  = x[r1 * 512 + d];
        xb2[j] = x[r2 * 512 + d];
    }
    float re[8], im[8];
#pragma unroll
    for (int j = 0; j < 8; j++) {
        int d = j * 64 + lane;
        int fd = __brev((unsigned)d) >> 23;
        int dp = __brev((unsigned)((512 - fd) & 511)) >> 23;
        float2 z1 = zb[d], z1p = zb[dp];
        float2 z2 = zb[512 + d], z2p = zb[512 + dp];
        float h1r = 0.5f * (z1.x + z1p.x), h1i = 0.5f * (z1.y - z1p.y);
        float h2r = 0.5f * (z2.x + z2p.x), h2i = 0.5f * (z2.y - z2p.y);
        re[j] = h1r - h2i;
        im[j] = h1i + h2r;
    }
    __syncthreads();
    for (int idx = tid; idx < 512; idx += 256) {
        int f = __brev((unsigned)idx) >> 23;
        int gg = (512 - f) & 511;
        float aa = (f == 0 || f == 256) ? 0.04419417382415922f : 0.0625f;
        float ah = aa * 0.5f;
        const float s5 = 0.5f * (1.0f / 512.0f);
        wbs[0 * 512 + idx] = ah * (qr[f] + qr[gg]); wbs[1 * 512 + idx] = ah * (qi[f] - qi[gg]);
        wbs[2 * 512 + idx] = ah * (kr[f] + kr[gg]); wbs[3 * 512 + idx] = ah * (ki[f] - ki[gg]);
        wbs[4 * 512 + idx] = s5 * (vr[f] + vr[gg]); wbs[5 * 512 + idx] = s5 * (vi[f] - vi[gg]);
    }

    wfft512<true>(re, im, tc, ts, lane);
    float a = alpha[0];
    float gre[8], gim[8];
#pragma unroll
    for (int j = 0; j < 8; j++) {
        int d = j * 64 + lane;
        float v1 = re[j] * (1.0f / 512.0f) + xa[j];
        float v2 = im[j] * (1.0f / 512.0f) + xb2[j];
        x1[r1 * 512 + d] = v1;
        x1[r2 * 512 + d] = v2;
        gre[j] = dyt_tanh(a * v1) * w[d] + bia[d];
        gim[j] = dyt_tanh(a * v2) * w[d] + bia[d];
    }
    wfft512<false>(gre, gim, tc, ts, lane);
    __syncthreads();

#pragma unroll
    for (int j = 0; j < 8; j++)
        zf[j * 64 + lane] = make_float2(gre[j], gim[j]);

    float pvr[8], pvi[8];
#pragma unroll
    for (int j = 0; j < 8; j++) {
        int i = j * 64 + lane;
        float wr0 = wbs[4 * 512 + i], wi0 = wbs[5 * 512 + i];
        pvr[j] = gre[j] * wr0 - gim[j] * wi0;
        pvi[j] = gre[j] * wi0 + gim[j] * wr0;
    }

    bool odd = (lane & 1) != 0;
#pragma unroll
    for (int j = 0; j < 8; j++) {
        int d = j * 64 + lane;
        int fd = __brev((unsigned)d) >> 23;
        int dp = __brev((unsigned)((512 - fd) & 511)) >> 23;
        float2 Zp = zf[dp];
        float zr = gre[j], zi = gim[j];
        float A1r = 0.5f * (zr + Zp.x), A1i = 0.5f * (zi - Zp.y);
        float A2r = 0.5f * (zi + Zp.y), A2i = 0.5f * (Zp.x - zr);
        float wr0 = wbs[0 * 512 + d], wi0 = wbs[1 * 512 + d];
        float Q1r = A1r * wr0 - A1i * wi0, Q1i = A1r * wi0 + A1i * wr0;
        float Q2r = A2r * wr0 - A2i * wi0, Q2i = A2r * wi0 + A2i * wr0;
        qb[r1 * 512 + d] = f2bf(odd ? -Q1i : Q1r);
        qb[r2 * 512 + d] = f2bf(odd ? -Q2i : Q2r);
        float wr1 = wbs[2 * 512 + d], wi1 = wbs[3 * 512 + d];
        float K1r = A1r * wr1 - A1i * wi1, K1i = A1r * wi1 + A1i * wr1;
        float K2r = A2r * wr1 - A2i * wi1, K2i = A2r * wi1 + A2i * wr1;
        kb[r1 * 512 + d] = f2bf(odd ? -K1i : K1r);
        kb[r2 * 512 + d] = f2bf(odd ? -K2i : K2r);
    }

    wfft512<true>(pvr, pvi, tc, ts, lane);
#pragma unroll
    for (int j = 0; j < 8; j++) {
        int d = j * 64 + lane;
        vb[r1 * 512 + d] = f2bf(pvr[j]);
        vb[r2 * 512 + d] = f2bf(pvi[j]);
    }
}

// ---------------- unified bt-GEMM (BK=64, global_load_lds, XOR-swizzled LDS) ----------------
__global__ __launch_bounds__(256) void gemm_bt(
        const unsigned short* __restrict__ A, const unsigned short* __restrict__ Bt,
        void* __restrict__ C, int M, int N, int Ks, int kseg, float scale, int out_half) {
    int tilesM = M >> 7, tilesN = N >> 7;
    int perBatch = tilesM * tilesN;
    int l = blockIdx.x;
    int seg = blockIdx.y;
    int s = l & 7, t = l >> 3;
    int cnt = perBatch >> 3;
    int bz = t / cnt;
    int u = t - bz * cnt;
    int pn = tilesN >> 1, pm = tilesM >> 2;
    int n0 = ((s & 1) * pn + (u % pn)) << 7;
    int m0 = ((s >> 1) * pm + (u / pn)) << 7;
    int kbase = seg * kseg;

    const unsigned short* Ab = A + (size_t)bz * M * Ks;
    const unsigned short* Bb = Bt + (size_t)bz * N * Ks;
    __shared__ __align__(16) unsigned short smem[2 * 128 * 64];
    unsigned short* As = smem;
    unsigned short* Bs = smem + 128 * 64;
    int tid = threadIdx.x;
    int wave = tid >> 6, lane = tid & 63;
    int wm = (wave >> 1) * 64, wn = (wave & 1) * 64;
    int lrow = lane & 15, lq = lane >> 4;
    floatx4 acc[4][4];
#pragma unroll
    for (int i = 0; i < 4; i++)
#pragma unroll
        for (int j = 0; j < 4; j++)
            acc[i][j] = (floatx4){0.f, 0.f, 0.f, 0.f};

    int lr = lane >> 3;
    int lcs = lane & 7;
    for (int k0 = kbase; k0 < kbase + kseg; k0 += 64) {
        __syncthreads();
#pragma unroll
        for (int i = 0; i < 4; i++) {
            int c = wave * 4 + i;
            int r = c * 8 + lr;
            int gcol = ((lcs ^ (r & 7)) << 3);
            async_load16(Ab + (size_t)(m0 + r) * Ks + k0 + gcol, As + c * 512);
            async_load16(Bb + (size_t)(n0 + r) * Ks + k0 + gcol, Bs + c * 512);
        }
        __syncthreads();
        bf16x8 a0[4], a1[4], b0[4], b1[4];
#pragma unroll
        for (int mi = 0; mi < 4; mi++) {
            int r = wm + mi * 16 + lrow;
            a0[mi] = *(const bf16x8*)(As + r * 64 + ((lq ^ (r & 7)) << 3));
            a1[mi] = *(const bf16x8*)(As + r * 64 + (((lq + 4) ^ (r & 7)) << 3));
        }
#pragma unroll
        for (int ni = 0; ni < 4; ni++) {
            int r = wn + ni * 16 + lrow;
            b0[ni] = *(const bf16x8*)(Bs + r * 64 + ((lq ^ (r & 7)) << 3));
            b1[ni] = *(const bf16x8*)(Bs + r * 64 + (((lq + 4) ^ (r & 7)) << 3));
        }
#pragma unroll
        for (int mi = 0; mi < 4; mi++)
#pragma unroll
            for (int ni = 0; ni < 4; ni++) {
                acc[mi][ni] = __builtin_amdgcn_mfma_f32_16x16x32_bf16(a0[mi], b0[ni], acc[mi][ni], 0, 0, 0);
                acc[mi][ni] = __builtin_amdgcn_mfma_f32_16x16x32_bf16(a1[mi], b1[ni], acc[mi][ni], 0, 0, 0);
            }
    }
    size_t cbase = ((size_t)seg * 4 + bz) * (size_t)M * N;
    int lr0 = (wave >> 1) * 16 + lq * 4;
    for (int mi = 0; mi < 4; mi++) {
        __syncthreads();
        if (out_half) {
            _Float16* Cs = (_Float16*)smem;
            for (int ni = 0; ni < 4; ni++)
                for (int r = 0; r < 4; r++)
                    Cs[(lr0 + r) * 128 + wn + ni * 16 + lrow] = (_Float16)(acc[mi][ni][r] * scale);
            __syncthreads();
            for (int h = 0; h < 2; h++) {
                int chunk = tid + h * 256;
                int rl = chunk >> 4, cb = (chunk & 15) * 16;
                int grow = m0 + mi * 16 + (rl & 15) + (rl >> 4) * 64;
                *(uint4*)((char*)C + (cbase + (size_t)grow * N + n0) * 2 + cb) =
                    *(const uint4*)((const char*)Cs + rl * 256 + cb);
            }
        } else {
            float* Cs = (float*)smem;
            for (int ni = 0; ni < 4; ni++)
                for (int r = 0; r < 4; r++)
                    Cs[(lr0 + r) * 128 + wn + ni * 16 + lrow] = acc[mi][ni][r] * scale;
            __syncthreads();
            for (int h = 0; h < 4; h++) {
                int chunk = tid + h * 256;
                int rl = chunk >> 5, cb = (chunk & 31) * 16;
                int grow = m0 + mi * 16 + (rl & 15) + (rl >> 4) * 64;
                *(uint4*)((char*)C + (cbase + (size_t)grow * N + n0) * 4 + cb) =
                    *(const uint4*)((const char*)Cs + rl * 512 + cb);
            }
        }
    }
}

// ---------------- softmax (in-place bf16 P) + v->vT transpose, one grid ----------------
__global__ __launch_bounds__(256) void sm_tr(
        const _Float16* __restrict__ Sc, unsigned short* __restrict__ P,
        const unsigned short* __restrict__ vb, unsigned short* __restrict__ vT) {
    __shared__ __align__(16) char lds[64 * 65 * 2];  // transpose tile; softmax uses first 16B
    if (blockIdx.x < 8192) {
        float* red = (float*)lds;
        int tid = threadIdx.x;
        size_t row = blockIdx.x;
        halfx8 hv = *(const halfx8*)(Sc + row * 2048 + tid * 8);
        float v[8];
#pragma unroll
        for (int j = 0; j < 8; j++) v[j] = (float)hv[j];
        float mx = v[0];
#pragma unroll
        for (int j = 1; j < 8; j++) mx = fmaxf(mx, v[j]);
        for (int off = 32; off >= 1; off >>= 1) mx = fmaxf(mx, __shfl_xor(mx, off));
        int wv = tid >> 6;
        if ((tid & 63) == 0) red[wv] = mx;
        __syncthreads();
        mx = fmaxf(fmaxf(red[0], red[1]), fmaxf(red[2], red[3]));
        float e[8], sum = 0.f;
#pragma unroll
        for (int j = 0; j < 8; j++) { e[j] = __expf(v[j] - mx); sum += e[j]; }
        for (int off = 32; off >= 1; off >>= 1) sum += __shfl_xor(sum, off);
        __syncthreads();
        if ((tid & 63) == 0) red[wv] = sum;
        __syncthreads();
        float inv = 1.0f / (red[0] + red[1] + red[2] + red[3]);
        ushortx8 o;
#pragma unroll
        for (int j = 0; j < 8; j++) o[j] = f2bf(e[j] * inv);
        *(ushortx8*)(P + row * 2048 + tid * 8) = o;
    } else {
        unsigned short (*tile)[65] = (unsigned short (*)[65])lds;
        int id = blockIdx.x - 8192;           // 1024 transpose blocks: (32, 8, 4)
        int sx = id & 31, dy = (id >> 5) & 7, bz = id >> 8;
        int s0 = sx * 64, d0 = dy * 64;
        int tx = threadIdx.x & 63, ty = threadIdx.x >> 6;
        for (int j = 0; j < 16; j++) {
            int s = ty + j * 4;
            tile[s][tx] = vb[((size_t)bz * 2048 + s0 + s) * 512 + d0 + tx];
        }
        __syncthreads();
        for (int j = 0; j < 16; j++) {
            int d = ty + j * 4;
            vT[((size_t)bz * 512 + d0 + d) * 2048 + s0 + tx] = tile[tx][d];
        }
    }
}

// ---------------- k5 : row-pair residual + dyt_f + spectral filter ----------------
// Sums TWO fp16 split-K partials.
__global__ __launch_bounds__(256, 4) void k5_ffn(
        const _Float16* __restrict__ attn0, const _Float16* __restrict__ attn1,
        const float* __restrict__ x1,
        const float* __restrict__ alpha, const float* __restrict__ w, const float* __restrict__ bia,
        const float* __restrict__ br, const float* __restrict__ bi,
        float* __restrict__ out) {
    __shared__ float wbs[2][512];
    int tid = threadIdx.x, lane = tid & 63, wv = tid >> 6;
    size_t pr = (size_t)blockIdx.x * 4 + wv;
    size_t r1 = pr * 2, r2 = r1 + 1;
    for (int idx = tid; idx < 512; idx += 256) {
        int f = __brev((unsigned)idx) >> 23;
        int gg = (512 - f) & 511;
        wbs[0][idx] = 0.5f * (br[f] + br[gg]) * (1.0f / 512.0f);
        wbs[1][idx] = 0.5f * (bi[f] - bi[gg]) * (1.0f / 512.0f);
    }
    float tc[12], ts[12];
    wtw512(tc, ts, lane);
    float a = alpha[0];
    float re[8], im[8], x2a[8], x2b[8];
#pragma unroll
    for (int j = 0; j < 8; j++) {
        int d = j * 64 + lane;
        float v1 = (float)attn0[r1 * 512 + d] + (float)attn1[r1 * 512 + d] + x1[r1 * 512 + d];
        float v2 = (float)attn0[r2 * 512 + d] + (float)attn1[r2 * 512 + d] + x1[r2 * 512 + d];
        x2a[j] = v1; x2b[j] = v2;
        re[j] = dyt_tanh(a * v1) * w[d] + bia[d];
        im[j] = dyt_tanh(a * v2) * w[d] + bia[d];
    }
    wfft512<false>(re, im, tc, ts, lane);
    __syncthreads();
#pragma unroll
    for (int j = 0; j < 8; j++) {
        int i = j * 64 + lane;
        float wr0 = wbs[0][i], wi0 = wbs[1][i];
        float rr = re[j], ii = im[j];
        re[j] = rr * wr0 - ii * wi0;
        im[j] = rr * wi0 + ii * wr0;
    }
    wfft512<true>(re, im, tc, ts, lane);
#pragma unroll
    for (int j = 0; j < 8; j++) {
        int d = j * 64 + lane;
        out[r1 * 512 + d] = re[j] + x2a[j];
        out[r2 * 512 + d] = im[j] + x2b[j];
    }
}

extern "C" void kernel_launch(void* const* d_in, const int* in_sizes, int n_in,
                              void* d_out, int out_size, void* d_ws, size_t ws_size,
                              hipStream_t stream) {
    const float* x      = (const float*)d_in[0];
    const float* a_qr   = (const float*)d_in[1];
    const float* a_kr   = (const float*)d_in[2];
    const float* a_vr   = (const float*)d_in[3];
    const float* a_rtr  = (const float*)d_in[4];
    const float* b_qr   = (const float*)d_in[5];
    const float* b_kr   = (const float*)d_in[6];
    const float* b_vr   = (const float*)d_in[7];
    /* f_ar = d_in[8] unused (dead gelu branch) */
    const float* f_br   = (const float*)d_in[9];
    const float* a_qi   = (const float*)d_in[10];
    const float* a_ki   = (const float*)d_in[11];
    const float* a_vi   = (const float*)d_in[12];
    const float* a_rti  = (const float*)d_in[13];
    const float* b_qi   = (const float*)d_in[14];
    const float* b_ki   = (const float*)d_in[15];
    const float* b_vi   = (const float*)d_in[16];
    /* f_ai = d_in[17] unused */
    const float* f_bi   = (const float*)d_in[18];
    /* f_bias = d_in[19] unused (dead gelu branch) */
    const float* dyta_alpha = (const float*)d_in[20];
    const float* dyta_w     = (const float*)d_in[21];
    const float* dyta_b     = (const float*)d_in[22];
    const float* dytb_alpha = (const float*)d_in[23];
    const float* dytb_w     = (const float*)d_in[24];
    const float* dytb_b     = (const float*)d_in[25];
    const float* dytf_alpha = (const float*)d_in[26];
    const float* dytf_w     = (const float*)d_in[27];
    const float* dytf_b     = (const float*)d_in[28];
    (void)in_sizes; (void)n_in; (void)out_size; (void)ws_size;

    char* ws = (char*)d_ws;
    const size_t MB = 1024 * 1024;
    half2v* xfH = (half2v*)(ws + 0 * MB);           // 16MB packed fp16 complex
    float* x1   = (float*)(ws + 32 * MB);           // 16MB
    unsigned short* qb = (unsigned short*)(ws + 48 * MB);  // 8MB
    unsigned short* kb = (unsigned short*)(ws + 56 * MB);  // 8MB
    unsigned short* vb = (unsigned short*)(ws + 64 * MB);  // 8MB
    unsigned short* vT = (unsigned short*)(ws + 72 * MB);  // 8MB
    _Float16* scores   = (_Float16*)(ws + 0 * MB);  // 32MB, overlays dead xfH
    unsigned short* Pb = (unsigned short*)(ws + 0 * MB);   // bf16 P, in place over scores
    _Float16* attnP    = (_Float16*)(ws + 81 * MB); // 16MB: two 8MB fp16 K-split partials
    float* outp = (float*)d_out;

    k1_dyt_fftd<<<2048, 256, 0, stream>>>(x, dyta_alpha, dyta_w, dyta_b, xfH);
    k2_sfft<<<1024, 512, 0, stream>>>(xfH, a_qr, a_qi, a_kr, a_ki, a_vr, a_vi, a_rtr, a_rti);
    k3_mid<<<1024, 256, 0, stream>>>(xfH, x, dytb_alpha, dytb_w, dytb_b,
                                     b_qr, b_qi, b_kr, b_ki, b_vr, b_vi, x1, qb, kb, vb);
    gemm_bt<<<1024, 256, 0, stream>>>(qb, kb, scores, 2048, 2048, 512, 512,
                                      0.04419417382415922f, 1);
    sm_tr<<<9216, 256, 0, stream>>>(scores, Pb, vb, vT);
    gemm_bt<<<dim3(256, 2), 256, 0, stream>>>(Pb, vT, attnP, 2048, 512, 2048, 1024,
                                              1.0f, 1);
    k5_ffn<<<1024, 256, 0, stream>>>(attnP, attnP + (size_t)4 * 2048 * 512, x1,
                                     dytf_alpha, dytf_w, dytf_b, f_br, f_bi, outp);
}

// Round 10
// 275.727 us; speedup vs baseline: 1.3950x; 1.0079x over previous
//
#include <hip/hip_runtime.h>

// B=4, S=2048, D=512, fp32 in/out. threshold 1.45e-1.
// Pipeline (Hermitian-packed D-FFTs: one 512-pt FFT serves TWO rows):
//  k1 : u=dyt_a(x); XfH = FFT_D(u)          (wave-register FFT, bitrev bins, half2 storage)
//  k2 : per column-PAIR: in-place radix-4 2048-pt S-FFT (fp32 LDS, fp16 global),
//       spectral op, exact inverse, *rtw/S. Twiddles from a 682-entry LDS table.
//  k3 : per ROW-PAIR: Hermitian combine, x1 (fp16, R27), dyt_b; q,k Parseval-
//       packed in the frequency domain; v packed inverse FFT.
//  g1 : scores = q@k^T
//  smtr: full softmax per row written in place as bf16 P + v->vT transpose.
//  g2 : attn = P@vT, split-K x2, fp16 partials.
//  k5 : row-pair residual (fp16 x1 + two fp16 partials) + dyt_f + spectral filter
// R27: x1 fp32->fp16 (the last fp32 intermediate): k3 writes 8MB not 16,
// k5 reads 8MB not 16 (-16MB total; R23 precedent: ~1.5us/32MB). Values are
// O(1); fp16 rounding ~1e-3 abs vs 0.145 threshold. Everything else identical
// to the 277.9us R26 baseline.
// k3 theory ledger (all refuted): DS-throughput (R21), +VALU-on-chain (R21,
// harmful), spills (R24), convoy/ILP (R25). k3 is latency/TLP-bound at its
// structural 4 waves/SIMD; GEMM region insensitive (+-3us over 5 variants).

typedef __attribute__((ext_vector_type(8))) __bf16 bf16x8;
typedef __attribute__((ext_vector_type(4))) float floatx4;
typedef __attribute__((ext_vector_type(8))) _Float16 halfx8;
typedef __attribute__((ext_vector_type(8))) unsigned short ushortx8;
typedef __attribute__((ext_vector_type(2))) _Float16 half2v;   // 4B packed complex (re,im)
typedef __attribute__((ext_vector_type(4))) _Float16 half4v;   // 8B = two packed complex

__device__ __forceinline__ unsigned short f2bf(float x) {
    unsigned u = __float_as_uint(x);
    u = (u + 0x7fffu + ((u >> 16) & 1u)) >> 16;
    return (unsigned short)u;
}

__device__ __forceinline__ float dyt_tanh(float x) {
    float e = __expf(2.0f * x);
    return 1.0f - 2.0f / (e + 1.0f);
}

__device__ __forceinline__ void async_load16(const unsigned short* g, unsigned short* l) {
    __builtin_amdgcn_global_load_lds(
        (const __attribute__((address_space(1))) unsigned int*)g,
        (__attribute__((address_space(3))) unsigned int*)l, 16, 0, 0);
}

// ---------- wave-level 512-pt FFT (8 pts/lane) ----------
__device__ __forceinline__ void wtw512(float (&tc)[12], float (&ts)[12], int lane) {
    const float w = -6.28318530717958647692f / 512.0f;
#pragma unroll
    for (int j = 0; j < 4; j++) __sincosf(w * (float)(j * 64 + lane), &ts[j], &tc[j]);
#pragma unroll
    for (int j = 0; j < 2; j++) __sincosf(w * (float)(2 * (j * 64 + lane)), &ts[4 + j], &tc[4 + j]);
    __sincosf(w * (float)(4 * lane), &ts[6], &tc[6]);
    __sincosf(w * (float)(8 * (lane & 31)), &ts[7], &tc[7]);
    __sincosf(w * (float)(16 * (lane & 15)), &ts[8], &tc[8]);
    __sincosf(w * (float)(32 * (lane & 7)), &ts[9], &tc[9]);
    __sincosf(w * (float)(64 * (lane & 3)), &ts[10], &tc[10]);
    __sincosf(w * (float)(128 * (lane & 1)), &ts[11], &tc[11]);
}

template <bool INV>
__device__ __forceinline__ void wfft512(float (&re)[8], float (&im)[8],
                                        const float (&tc)[12], const float (&ts)[12], int lane) {
    if (!INV) {
#pragma unroll
        for (int j = 0; j < 4; j++) {
            float ur = re[j], ui = im[j], vr = re[j + 4], vi = im[j + 4];
            re[j] = ur + vr; im[j] = ui + vi;
            float dr = ur - vr, di = ui - vi;
            re[j + 4] = dr * tc[j] - di * ts[j];
            im[j + 4] = dr * ts[j] + di * tc[j];
        }
#pragma unroll
        for (int g = 0; g < 8; g += 4)
#pragma unroll
            for (int jj = 0; jj < 2; jj++) {
                int j = g + jj;
                float ur = re[j], ui = im[j], vr = re[j + 2], vi = im[j + 2];
                re[j] = ur + vr; im[j] = ui + vi;
                float dr = ur - vr, di = ui - vi;
                re[j + 2] = dr * tc[4 + jj] - di * ts[4 + jj];
                im[j + 2] = dr * ts[4 + jj] + di * tc[4 + jj];
            }
#pragma unroll
        for (int j = 0; j < 8; j += 2) {
            float ur = re[j], ui = im[j], vr = re[j + 1], vi = im[j + 1];
            re[j] = ur + vr; im[j] = ui + vi;
            float dr = ur - vr, di = ui - vi;
            re[j + 1] = dr * tc[6] - di * ts[6];
            im[j + 1] = dr * ts[6] + di * tc[6];
        }
#pragma unroll
        for (int st = 0; st < 6; st++) {
            int h = 32 >> st;
            bool hi = (lane & h) != 0;
            float c = (st < 5) ? tc[7 + st] : 1.0f;
            float s = (st < 5) ? ts[7 + st] : 0.0f;
#pragma unroll
            for (int j = 0; j < 8; j++) {
                float orr = __shfl_xor(re[j], h, 64);
                float oii = __shfl_xor(im[j], h, 64);
                float dr = orr - re[j], di = oii - im[j];
                float sr = re[j] + orr, si = im[j] + oii;
                re[j] = hi ? (dr * c - di * s) : sr;
                im[j] = hi ? (dr * s + di * c) : si;
            }
        }
    } else {
#pragma unroll
        for (int st = 5; st >= 0; st--) {
            int h = 32 >> st;
            bool hi = (lane & h) != 0;
            float c = (st < 5) ? tc[7 + st] : 1.0f;
            float s = (st < 5) ? ts[7 + st] : 0.0f;
#pragma unroll
            for (int j = 0; j < 8; j++) {
                float zr = re[j], zi = im[j];
                float vr = zr * c + zi * s;
                float vi = zi * c - zr * s;
                float mr = hi ? vr : zr;
                float mi = hi ? vi : zi;
                float orr = __shfl_xor(mr, h, 64);
                float oii = __shfl_xor(mi, h, 64);
                re[j] = hi ? (orr - vr) : (zr + orr);
                im[j] = hi ? (oii - vi) : (zi + oii);
            }
        }
#pragma unroll
        for (int j = 0; j < 8; j += 2) {
            float vr = re[j + 1] * tc[6] + im[j + 1] * ts[6];
            float vi = im[j + 1] * tc[6] - re[j + 1] * ts[6];
            re[j + 1] = re[j] - vr; im[j + 1] = im[j] - vi;
            re[j] += vr; im[j] += vi;
        }
#pragma unroll
        for (int g = 0; g < 8; g += 4)
#pragma unroll
            for (int jj = 0; jj < 2; jj++) {
                int j = g + jj;
                float vr = re[j + 2] * tc[4 + jj] + im[j + 2] * ts[4 + jj];
                float vi = im[j + 2] * tc[4 + jj] - re[j + 2] * ts[4 + jj];
                re[j + 2] = re[j] - vr; im[j + 2] = im[j] - vi;
                re[j] += vr; im[j] += vi;
            }
#pragma unroll
        for (int j = 0; j < 4; j++) {
            float vr = re[j + 4] * tc[j] + im[j + 4] * ts[j];
            float vi = im[j + 4] * tc[j] - re[j + 4] * ts[j];
            re[j + 4] = re[j] - vr; im[j + 4] = im[j] - vi;
            re[j] += vr; im[j] += vi;
        }
    }
}

// ---------------- k1 : dyt_a + forward D-FFT (half2 output) ----------------
__global__ __launch_bounds__(256, 4) void k1_dyt_fftd(
        const float* __restrict__ x,
        const float* __restrict__ alpha, const float* __restrict__ w, const float* __restrict__ bia,
        half2v* __restrict__ xf) {
    int tid = threadIdx.x, lane = tid & 63, wv = tid >> 6;
    size_t row = (size_t)blockIdx.x * 4 + wv;
    float tc[12], ts[12];
    wtw512(tc, ts, lane);
    float re[8], im[8];
    float a = alpha[0];
    const float* xr = x + row * 512;
#pragma unroll
    for (int j = 0; j < 8; j++) {
        int d = j * 64 + lane;
        re[j] = dyt_tanh(a * xr[d]) * w[d] + bia[d];
        im[j] = 0.f;
    }
    wfft512<false>(re, im, tc, ts, lane);
#pragma unroll
    for (int j = 0; j < 8; j++) {
        int d = j * 64 + lane;
        xf[row * 512 + d] = (half2v){(_Float16)re[j], (_Float16)im[j]};
    }
}

// ---------------- k2 : in-place radix-4 2048-pt S-FFT, 2 cols/block ----------------
__device__ __forceinline__ int pidx4(int i) { return i + (i >> 3); }

// Both fwd and inv read the SAME table entry (c,s) = sincos(-2*pi*pos/(4h));
// inv applies the conjugate internally (u = y*(c - i*s)).
__device__ __forceinline__ void r4_fwd(float4* X, int t, int h, const half2v* tw) {
    int pos = t & (h - 1);
    int i = ((t & ~(h - 1)) << 2) | pos;
    int i0 = pidx4(i), i1 = pidx4(i + h), i2 = pidx4(i + 2 * h), i3 = pidx4(i + 3 * h);
    float4 a0 = X[i0], a1 = X[i1], a2 = X[i2], a3 = X[i3];
    half2v wv = tw[pos];
    float c1 = (float)wv.x, s1 = (float)wv.y;
    float c2 = c1 * c1 - s1 * s1, s2 = 2.f * c1 * s1;
    float c3 = c2 * c1 - s2 * s1, s3 = s2 * c1 + c2 * s1;
    float4 o0, o1, o2, o3;
    {
        float t0r = a0.x + a2.x, t0i = a0.y + a2.y, t1r = a0.x - a2.x, t1i = a0.y - a2.y;
        float t2r = a1.x + a3.x, t2i = a1.y + a3.y, t3r = a1.x - a3.x, t3i = a1.y - a3.y;
        o0.x = t0r + t2r; o0.y = t0i + t2i;
        float b1r = t1r + t3i, b1i = t1i - t3r;
        float b2r = t0r - t2r, b2i = t0i - t2i;
        float b3r = t1r - t3i, b3i = t1i + t3r;
        o1.x = b1r * c1 - b1i * s1; o1.y = b1r * s1 + b1i * c1;
        o2.x = b2r * c2 - b2i * s2; o2.y = b2r * s2 + b2i * c2;
        o3.x = b3r * c3 - b3i * s3; o3.y = b3r * s3 + b3i * c3;
    }
    {
        float t0r = a0.z + a2.z, t0i = a0.w + a2.w, t1r = a0.z - a2.z, t1i = a0.w - a2.w;
        float t2r = a1.z + a3.z, t2i = a1.w + a3.w, t3r = a1.z - a3.z, t3i = a1.w - a3.w;
        o0.z = t0r + t2r; o0.w = t0i + t2i;
        float b1r = t1r + t3i, b1i = t1i - t3r;
        float b2r = t0r - t2r, b2i = t0i - t2i;
        float b3r = t1r - t3i, b3i = t1i + t3r;
        o1.z = b1r * c1 - b1i * s1; o1.w = b1r * s1 + b1i * c1;
        o2.z = b2r * c2 - b2i * s2; o2.w = b2r * s2 + b2i * c2;
        o3.z = b3r * c3 - b3i * s3; o3.w = b3r * s3 + b3i * c3;
    }
    X[i0] = o0; X[i1] = o1; X[i2] = o2; X[i3] = o3;
}

__device__ __forceinline__ void r4_inv(float4* X, int t, int h, const half2v* tw) {
    int pos = t & (h - 1);
    int i = ((t & ~(h - 1)) << 2) | pos;
    int i0 = pidx4(i), i1 = pidx4(i + h), i2 = pidx4(i + 2 * h), i3 = pidx4(i + 3 * h);
    float4 y0 = X[i0], y1 = X[i1], y2 = X[i2], y3 = X[i3];
    half2v wv = tw[pos];
    float c1 = (float)wv.x, s1 = (float)wv.y;
    float c2 = c1 * c1 - s1 * s1, s2 = 2.f * c1 * s1;
    float c3 = c2 * c1 - s2 * s1, s3 = s2 * c1 + c2 * s1;
    float4 o0, o1, o2, o3;
    {
        float u1r = y1.x * c1 + y1.y * s1, u1i = y1.y * c1 - y1.x * s1;
        float u2r = y2.x * c2 + y2.y * s2, u2i = y2.y * c2 - y2.x * s2;
        float u3r = y3.x * c3 + y3.y * s3, u3i = y3.y * c3 - y3.x * s3;
        float s0r = y0.x + u2r, s0i = y0.y + u2i;
        float s1r = y0.x - u2r, s1i = y0.y - u2i;
        float s2r = u1r + u3r, s2i = u1i + u3i;
        float s3r = u1r - u3r, s3i = u1i - u3i;
        o0.x = s0r + s2r; o0.y = s0i + s2i;
        o2.x = s0r - s2r; o2.y = s0i - s2i;
        o1.x = s1r - s3i; o1.y = s1i + s3r;
        o3.x = s1r + s3i; o3.y = s1i - s3r;
    }
    {
        float u1r = y1.z * c1 + y1.w * s1, u1i = y1.w * c1 - y1.z * s1;
        float u2r = y2.z * c2 + y2.w * s2, u2i = y2.w * c2 - y2.z * s2;
        float u3r = y3.z * c3 + y3.w * s3, u3i = y3.w * c3 - y3.z * s3;
        float s0r = y0.z + u2r, s0i = y0.w + u2i;
        float s1r = y0.z - u2r, s1i = y0.w - u2i;
        float s2r = u1r + u3r, s2i = u1i + u3i;
        float s3r = u1r - u3r, s3i = u1i - u3i;
        o0.z = s0r + s2r; o0.w = s0i + s2i;
        o2.z = s0r - s2r; o2.w = s0i - s2i;
        o1.z = s1r - s3i; o1.w = s1i + s3r;
        o3.z = s1r + s3i; o3.w = s1i - s3r;
    }
    X[i0] = o0; X[i1] = o1; X[i2] = o2; X[i3] = o3;
}

__global__ __launch_bounds__(512) void k2_sfft(
        half2v* __restrict__ xf,
        const float* __restrict__ qr, const float* __restrict__ qi,
        const float* __restrict__ kr, const float* __restrict__ ki,
        const float* __restrict__ vr, const float* __restrict__ vi,
        const float* __restrict__ rtr, const float* __restrict__ rti) {
    __shared__ float4 buf[2304];
    __shared__ half2v twd[682];   // fwd twiddles: h=512@0, 128@512, 32@640, 8@672, 2@680
    int t = threadIdx.x;
    int g = blockIdx.x;
    int xcd = g & 7, r = g >> 3;
    int pp = xcd * 32 + (r & 31);
    int b = r >> 5;
    int p0 = pp * 2;
    half4v* colh = (half4v*)(xf + (size_t)b * 2048 * 512 + p0);

    // cooperative twiddle-table fill (2 passes over 512 threads)
    for (int i = t; i < 682; i += 512) {
        int h, off;
        if (i < 512)      { h = 512; off = 0; }
        else if (i < 640) { h = 128; off = 512; }
        else if (i < 672) { h = 32;  off = 640; }
        else if (i < 680) { h = 8;   off = 672; }
        else              { h = 2;   off = 680; }
        int pos = i - off;
        float s, c;
        __sincosf(-6.28318530717958647692f * (float)pos / (float)(4 * h), &s, &c);
        twd[i] = (half2v){(_Float16)c, (_Float16)s};
    }

#pragma unroll
    for (int c = 0; c < 4; c++) {
        int s = t + 512 * c;
        half4v h = colh[(size_t)s * 256];
        buf[pidx4(s)] = make_float4((float)h.x, (float)h.y, (float)h.z, (float)h.w);
    }
    __syncthreads(); r4_fwd(buf, t, 512, twd);
    __syncthreads(); r4_fwd(buf, t, 128, twd + 512);
    __syncthreads(); r4_fwd(buf, t, 32, twd + 640);
    __syncthreads(); r4_fwd(buf, t, 8, twd + 672);
    __syncthreads(); r4_fwd(buf, t, 2, twd + 680);
    __syncthreads();
#pragma unroll
    for (int c = 0; c < 2; c++) {
        int pr = t + 512 * c;
        int ia = pidx4(2 * pr), ib = pidx4(2 * pr + 1);
        float4 a = buf[ia], bb = buf[ib];
        buf[ia] = make_float4(a.x + bb.x, a.y + bb.y, a.z + bb.z, a.w + bb.w);
        buf[ib] = make_float4(a.x - bb.x, a.y - bb.y, a.z - bb.z, a.w - bb.w);
    }
    __syncthreads();

    int f0 = __brev((unsigned)p0) >> 23;
    int f1 = __brev((unsigned)(p0 + 1)) >> 23;
    float qw0r = qr[f0], qw0i = qi[f0], kw0r = kr[f0], kw0i = ki[f0], vw0r = vr[f0], vw0i = vi[f0];
    float qw1r = qr[f1], qw1i = qi[f1], kw1r = kr[f1], kw1i = ki[f1], vw1r = vr[f1], vw1i = vi[f1];
#pragma unroll
    for (int c = 0; c < 4; c++) {
        int idx = pidx4(t + 512 * c);
        float4 y = buf[idx];
        {
            float yr = y.x, yi = y.y;
            float qre = yr * qw0r - yi * qw0i, qim = yr * qw0i + yi * qw0r;
            float kre = yr * kw0r - yi * kw0i + 1e-12f, kim = yr * kw0i + yi * kw0r;
            float vre = yr * vw0r - yi * vw0i, vim = yr * vw0i + yi * vw0r;
            float inv = 1.0f / (kre * kre + kim * kim);
            float dre = (qre * kre + qim * kim) * inv;
            float dim = (qim * kre - qre * kim) * inv;
            y.x = dre * vre - dim * vim;
            y.y = dre * vim + dim * vre;
        }
        {
            float yr = y.z, yi = y.w;
            float qre = yr * qw1r - yi * qw1i, qim = yr * qw1i + yi * qw1r;
            float kre = yr * kw1r - yi * kw1i + 1e-12f, kim = yr * kw1i + yi * kw1r;
            float vre = yr * vw1r - yi * vw1i, vim = yr * vw1i + yi * vw1r;
            float inv = 1.0f / (kre * kre + kim * kim);
            float dre = (qre * kre + qim * kim) * inv;
            float dim = (qim * kre - qre * kim) * inv;
            y.z = dre * vre - dim * vim;
            y.w = dre * vim + dim * vre;
        }
        buf[idx] = y;
    }

    __syncthreads();
#pragma unroll
    for (int c = 0; c < 2; c++) {
        int pr = t + 512 * c;
        int ia = pidx4(2 * pr), ib = pidx4(2 * pr + 1);
        float4 a = buf[ia], bb = buf[ib];
        buf[ia] = make_float4(a.x + bb.x, a.y + bb.y, a.z + bb.z, a.w + bb.w);
        buf[ib] = make_float4(a.x - bb.x, a.y - bb.y, a.z - bb.z, a.w - bb.w);
    }
    __syncthreads(); r4_inv(buf, t, 2, twd + 680);
    __syncthreads(); r4_inv(buf, t, 8, twd + 672);
    __syncthreads(); r4_inv(buf, t, 32, twd + 640);
    __syncthreads(); r4_inv(buf, t, 128, twd + 512);
    __syncthreads(); r4_inv(buf, t, 512, twd);
    __syncthreads();

    const float sc = 1.0f / 2048.0f;
    float r0r = rtr[f0] * sc, r0i = rti[f0] * sc;
    float r1r = rtr[f1] * sc, r1i = rti[f1] * sc;
#pragma unroll
    for (int c = 0; c < 4; c++) {
        int s = t + 512 * c;
        float4 z = buf[pidx4(s)];
        float ox = z.x * r0r - z.y * r0i, oy = z.x * r0i + z.y * r0r;
        float oz = z.z * r1r - z.w * r1i, ow = z.z * r1i + z.w * r1r;
        colh[(size_t)s * 256] = (half4v){(_Float16)ox, (_Float16)oy, (_Float16)oz, (_Float16)ow};
    }
}

// ---------------- k3 : row-pair residual + dyt_b + q/k (Parseval-packed) + v ----------------
__global__ __launch_bounds__(256, 4) void k3_mid(
        const half2v* __restrict__ xf,
        const float* __restrict__ x,
        const float* __restrict__ alpha, const float* __restrict__ w, const float* __restrict__ bia,
        const float* __restrict__ qr, const float* __restrict__ qi,
        const float* __restrict__ kr, const float* __restrict__ ki,
        const float* __restrict__ vr, const float* __restrict__ vi,
        _Float16* __restrict__ x1,
        unsigned short* __restrict__ qb, unsigned short* __restrict__ kb, unsigned short* __restrict__ vb) {
    __shared__ __align__(16) char smem[4 * 1024 * 8];  // 32KB
    int tid = threadIdx.x, lane = tid & 63, wv = tid >> 6;
    float2* zb = (float2*)(smem + wv * 8192);          // phase1: wave-private 8KB
    float* wbs = (float*)smem;                          // [6][512]=12KB (after combine)
    float2* zf = (float2*)(smem + 12288 + wv * 4096);  // phase2: wave-private 4KB
    size_t pr = (size_t)blockIdx.x * 4 + wv;
    size_t r1 = pr * 2, r2 = r1 + 1;
    float tc[12], ts[12];
    wtw512(tc, ts, lane);

    float xa[8], xb2[8];
#pragma unroll
    for (int j = 0; j < 8; j++) {
        int d = j * 64 + lane;
        half2v h1 = xf[r1 * 512 + d];
        half2v h2 = xf[r2 * 512 + d];
        zb[d]       = make_float2((float)h1.x, (float)h1.y);
        zb[512 + d] = make_float2((float)h2.x, (float)h2.y);
        xa[j]  = x[r1 * 512 + d];
        xb2[j] = x[r2 * 512 + d];
    }
    float re[8], im[8];
#pragma unroll
    for (int j = 0; j < 8; j++) {
        int d = j * 64 + lane;
        int fd = __brev((unsigned)d) >> 23;
        int dp = __brev((unsigned)((512 - fd) & 511)) >> 23;
        float2 z1 = zb[d], z1p = zb[dp];
        float2 z2 = zb[512 + d], z2p = zb[512 + dp];
        float h1r = 0.5f * (z1.x + z1p.x), h1i = 0.5f * (z1.y - z1p.y);
        float h2r = 0.5f * (z2.x + z2p.x), h2i = 0.5f * (z2.y - z2p.y);
        re[j] = h1r - h2i;
        im[j] = h1i + h2r;
    }
    __syncthreads();
    for (int idx = tid; idx < 512; idx += 256) {
        int f = __brev((unsigned)idx) >> 23;
        int gg = (512 - f) & 511;
        float aa = (f == 0 || f == 256) ? 0.04419417382415922f : 0.0625f;
        float ah = aa * 0.5f;
        const float s5 = 0.5f * (1.0f / 512.0f);
        wbs[0 * 512 + idx] = ah * (qr[f] + qr[gg]); wbs[1 * 512 + idx] = ah * (qi[f] - qi[gg]);
        wbs[2 * 512 + idx] = ah * (kr[f] + kr[gg]); wbs[3 * 512 + idx] = ah * (ki[f] - ki[gg]);
        wbs[4 * 512 + idx] = s5 * (vr[f] + vr[gg]); wbs[5 * 512 + idx] = s5 * (vi[f] - vi[gg]);
    }

    wfft512<true>(re, im, tc, ts, lane);
    float a = alpha[0];
    float gre[8], gim[8];
#pragma unroll
    for (int j = 0; j < 8; j++) {
        int d = j * 64 + lane;
        float v1 = re[j] * (1.0f / 512.0f) + xa[j];
        float v2 = im[j] * (1.0f / 512.0f) + xb2[j];
        x1[r1 * 512 + d] = (_Float16)v1;
        x1[r2 * 512 + d] = (_Float16)v2;
        gre[j] = dyt_tanh(a * v1) * w[d] + bia[d];
        gim[j] = dyt_tanh(a * v2) * w[d] + bia[d];
    }
    wfft512<false>(gre, gim, tc, ts, lane);
    __syncthreads();

#pragma unroll
    for (int j = 0; j < 8; j++)
        zf[j * 64 + lane] = make_float2(gre[j], gim[j]);

    float pvr[8], pvi[8];
#pragma unroll
    for (int j = 0; j < 8; j++) {
        int i = j * 64 + lane;
        float wr0 = wbs[4 * 512 + i], wi0 = wbs[5 * 512 + i];
        pvr[j] = gre[j] * wr0 - gim[j] * wi0;
        pvi[j] = gre[j] * wi0 + gim[j] * wr0;
    }

    bool odd = (lane & 1) != 0;
#pragma unroll
    for (int j = 0; j < 8; j++) {
        int d = j * 64 + lane;
        int fd = __brev((unsigned)d) >> 23;
        int dp = __brev((unsigned)((512 - fd) & 511)) >> 23;
        float2 Zp = zf[dp];
        float zr = gre[j], zi = gim[j];
        float A1r = 0.5f * (zr + Zp.x), A1i = 0.5f * (zi - Zp.y);
        float A2r = 0.5f * (zi + Zp.y), A2i = 0.5f * (Zp.x - zr);
        float wr0 = wbs[0 * 512 + d], wi0 = wbs[1 * 512 + d];
        float Q1r = A1r * wr0 - A1i * wi0, Q1i = A1r * wi0 + A1i * wr0;
        float Q2r = A2r * wr0 - A2i * wi0, Q2i = A2r * wi0 + A2i * wr0;
        qb[r1 * 512 + d] = f2bf(odd ? -Q1i : Q1r);
        qb[r2 * 512 + d] = f2bf(odd ? -Q2i : Q2r);
        float wr1 = wbs[2 * 512 + d], wi1 = wbs[3 * 512 + d];
        float K1r = A1r * wr1 - A1i * wi1, K1i = A1r * wi1 + A1i * wr1;
        float K2r = A2r * wr1 - A2i * wi1, K2i = A2r * wi1 + A2i * wr1;
        kb[r1 * 512 + d] = f2bf(odd ? -K1i : K1r);
        kb[r2 * 512 + d] = f2bf(odd ? -K2i : K2r);
    }

    wfft512<true>(pvr, pvi, tc, ts, lane);
#pragma unroll
    for (int j = 0; j < 8; j++) {
        int d = j * 64 + lane;
        vb[r1 * 512 + d] = f2bf(pvr[j]);
        vb[r2 * 512 + d] = f2bf(pvi[j]);
    }
}

// ---------------- unified bt-GEMM (BK=64, global_load_lds, XOR-swizzled LDS) ----------------
__global__ __launch_bounds__(256) void gemm_bt(
        const unsigned short* __restrict__ A, const unsigned short* __restrict__ Bt,
        void* __restrict__ C, int M, int N, int Ks, int kseg, float scale, int out_half) {
    int tilesM = M >> 7, tilesN = N >> 7;
    int perBatch = tilesM * tilesN;
    int l = blockIdx.x;
    int seg = blockIdx.y;
    int s = l & 7, t = l >> 3;
    int cnt = perBatch >> 3;
    int bz = t / cnt;
    int u = t - bz * cnt;
    int pn = tilesN >> 1, pm = tilesM >> 2;
    int n0 = ((s & 1) * pn + (u % pn)) << 7;
    int m0 = ((s >> 1) * pm + (u / pn)) << 7;
    int kbase = seg * kseg;

    const unsigned short* Ab = A + (size_t)bz * M * Ks;
    const unsigned short* Bb = Bt + (size_t)bz * N * Ks;
    __shared__ __align__(16) unsigned short smem[2 * 128 * 64];
    unsigned short* As = smem;
    unsigned short* Bs = smem + 128 * 64;
    int tid = threadIdx.x;
    int wave = tid >> 6, lane = tid & 63;
    int wm = (wave >> 1) * 64, wn = (wave & 1) * 64;
    int lrow = lane & 15, lq = lane >> 4;
    floatx4 acc[4][4];
#pragma unroll
    for (int i = 0; i < 4; i++)
#pragma unroll
        for (int j = 0; j < 4; j++)
            acc[i][j] = (floatx4){0.f, 0.f, 0.f, 0.f};

    int lr = lane >> 3;
    int lcs = lane & 7;
    for (int k0 = kbase; k0 < kbase + kseg; k0 += 64) {
        __syncthreads();
#pragma unroll
        for (int i = 0; i < 4; i++) {
            int c = wave * 4 + i;
            int r = c * 8 + lr;
            int gcol = ((lcs ^ (r & 7)) << 3);
            async_load16(Ab + (size_t)(m0 + r) * Ks + k0 + gcol, As + c * 512);
            async_load16(Bb + (size_t)(n0 + r) * Ks + k0 + gcol, Bs + c * 512);
        }
        __syncthreads();
        bf16x8 a0[4], a1[4], b0[4], b1[4];
#pragma unroll
        for (int mi = 0; mi < 4; mi++) {
            int r = wm + mi * 16 + lrow;
            a0[mi] = *(const bf16x8*)(As + r * 64 + ((lq ^ (r & 7)) << 3));
            a1[mi] = *(const bf16x8*)(As + r * 64 + (((lq + 4) ^ (r & 7)) << 3));
        }
#pragma unroll
        for (int ni = 0; ni < 4; ni++) {
            int r = wn + ni * 16 + lrow;
            b0[ni] = *(const bf16x8*)(Bs + r * 64 + ((lq ^ (r & 7)) << 3));
            b1[ni] = *(const bf16x8*)(Bs + r * 64 + (((lq + 4) ^ (r & 7)) << 3));
        }
#pragma unroll
        for (int mi = 0; mi < 4; mi++)
#pragma unroll
            for (int ni = 0; ni < 4; ni++) {
                acc[mi][ni] = __builtin_amdgcn_mfma_f32_16x16x32_bf16(a0[mi], b0[ni], acc[mi][ni], 0, 0, 0);
                acc[mi][ni] = __builtin_amdgcn_mfma_f32_16x16x32_bf16(a1[mi], b1[ni], acc[mi][ni], 0, 0, 0);
            }
    }
    size_t cbase = ((size_t)seg * 4 + bz) * (size_t)M * N;
    int lr0 = (wave >> 1) * 16 + lq * 4;
    for (int mi = 0; mi < 4; mi++) {
        __syncthreads();
        if (out_half) {
            _Float16* Cs = (_Float16*)smem;
            for (int ni = 0; ni < 4; ni++)
                for (int r = 0; r < 4; r++)
                    Cs[(lr0 + r) * 128 + wn + ni * 16 + lrow] = (_Float16)(acc[mi][ni][r] * scale);
            __syncthreads();
            for (int h = 0; h < 2; h++) {
                int chunk = tid + h * 256;
                int rl = chunk >> 4, cb = (chunk & 15) * 16;
                int grow = m0 + mi * 16 + (rl & 15) + (rl >> 4) * 64;
                *(uint4*)((char*)C + (cbase + (size_t)grow * N + n0) * 2 + cb) =
                    *(const uint4*)((const char*)Cs + rl * 256 + cb);
            }
        } else {
            float* Cs = (float*)smem;
            for (int ni = 0; ni < 4; ni++)
                for (int r = 0; r < 4; r++)
                    Cs[(lr0 + r) * 128 + wn + ni * 16 + lrow] = acc[mi][ni][r] * scale;
            __syncthreads();
            for (int h = 0; h < 4; h++) {
                int chunk = tid + h * 256;
                int rl = chunk >> 5, cb = (chunk & 31) * 16;
                int grow = m0 + mi * 16 + (rl & 15) + (rl >> 4) * 64;
                *(uint4*)((char*)C + (cbase + (size_t)grow * N + n0) * 4 + cb) =
                    *(const uint4*)((const char*)Cs + rl * 512 + cb);
            }
        }
    }
}

// ---------------- softmax (in-place bf16 P) + v->vT transpose, one grid ----------------
__global__ __launch_bounds__(256) void sm_tr(
        const _Float16* __restrict__ Sc, unsigned short* __restrict__ P,
        const unsigned short* __restrict__ vb, unsigned short* __restrict__ vT) {
    __shared__ __align__(16) char lds[64 * 65 * 2];  // transpose tile; softmax uses first 16B
    if (blockIdx.x < 8192) {
        float* red = (float*)lds;
        int tid = threadIdx.x;
        size_t row = blockIdx.x;
        halfx8 hv = *(const halfx8*)(Sc + row * 2048 + tid * 8);
        float v[8];
#pragma unroll
        for (int j = 0; j < 8; j++) v[j] = (float)hv[j];
        float mx = v[0];
#pragma unroll
        for (int j = 1; j < 8; j++) mx = fmaxf(mx, v[j]);
        for (int off = 32; off >= 1; off >>= 1) mx = fmaxf(mx, __shfl_xor(mx, off));
        int wv = tid >> 6;
        if ((tid & 63) == 0) red[wv] = mx;
        __syncthreads();
        mx = fmaxf(fmaxf(red[0], red[1]), fmaxf(red[2], red[3]));
        float e[8], sum = 0.f;
#pragma unroll
        for (int j = 0; j < 8; j++) { e[j] = __expf(v[j] - mx); sum += e[j]; }
        for (int off = 32; off >= 1; off >>= 1) sum += __shfl_xor(sum, off);
        __syncthreads();
        if ((tid & 63) == 0) red[wv] = sum;
        __syncthreads();
        float inv = 1.0f / (red[0] + red[1] + red[2] + red[3]);
        ushortx8 o;
#pragma unroll
        for (int j = 0; j < 8; j++) o[j] = f2bf(e[j] * inv);
        *(ushortx8*)(P + row * 2048 + tid * 8) = o;
    } else {
        unsigned short (*tile)[65] = (unsigned short (*)[65])lds;
        int id = blockIdx.x - 8192;           // 1024 transpose blocks: (32, 8, 4)
        int sx = id & 31, dy = (id >> 5) & 7, bz = id >> 8;
        int s0 = sx * 64, d0 = dy * 64;
        int tx = threadIdx.x & 63, ty = threadIdx.x >> 6;
        for (int j = 0; j < 16; j++) {
            int s = ty + j * 4;
            tile[s][tx] = vb[((size_t)bz * 2048 + s0 + s) * 512 + d0 + tx];
        }
        __syncthreads();
        for (int j = 0; j < 16; j++) {
            int d = ty + j * 4;
            vT[((size_t)bz * 512 + d0 + d) * 2048 + s0 + tx] = tile[tx][d];
        }
    }
}

// ---------------- k5 : row-pair residual + dyt_f + spectral filter ----------------
// Sums TWO fp16 split-K partials + fp16 x1 residual (R27).
__global__ __launch_bounds__(256, 4) void k5_ffn(
        const _Float16* __restrict__ attn0, const _Float16* __restrict__ attn1,
        const _Float16* __restrict__ x1,
        const float* __restrict__ alpha, const float* __restrict__ w, const float* __restrict__ bia,
        const float* __restrict__ br, const float* __restrict__ bi,
        float* __restrict__ out) {
    __shared__ float wbs[2][512];
    int tid = threadIdx.x, lane = tid & 63, wv = tid >> 6;
    size_t pr = (size_t)blockIdx.x * 4 + wv;
    size_t r1 = pr * 2, r2 = r1 + 1;
    for (int idx = tid; idx < 512; idx += 256) {
        int f = __brev((unsigned)idx) >> 23;
        int gg = (512 - f) & 511;
        wbs[0][idx] = 0.5f * (br[f] + br[gg]) * (1.0f / 512.0f);
        wbs[1][idx] = 0.5f * (bi[f] - bi[gg]) * (1.0f / 512.0f);
    }
    float tc[12], ts[12];
    wtw512(tc, ts, lane);
    float a = alpha[0];
    float re[8], im[8], x2a[8], x2b[8];
#pragma unroll
    for (int j = 0; j < 8; j++) {
        int d = j * 64 + lane;
        float v1 = (float)attn0[r1 * 512 + d] + (float)attn1[r1 * 512 + d] + (float)x1[r1 * 512 + d];
        float v2 = (float)attn0[r2 * 512 + d] + (float)attn1[r2 * 512 + d] + (float)x1[r2 * 512 + d];
        x2a[j] = v1; x2b[j] = v2;
        re[j] = dyt_tanh(a * v1) * w[d] + bia[d];
        im[j] = dyt_tanh(a * v2) * w[d] + bia[d];
    }
    wfft512<false>(re, im, tc, ts, lane);
    __syncthreads();
#pragma unroll
    for (int j = 0; j < 8; j++) {
        int i = j * 64 + lane;
        float wr0 = wbs[0][i], wi0 = wbs[1][i];
        float rr = re[j], ii = im[j];
        re[j] = rr * wr0 - ii * wi0;
        im[j] = rr * wi0 + ii * wr0;
    }
    wfft512<true>(re, im, tc, ts, lane);
#pragma unroll
    for (int j = 0; j < 8; j++) {
        int d = j * 64 + lane;
        out[r1 * 512 + d] = re[j] + x2a[j];
        out[r2 * 512 + d] = im[j] + x2b[j];
    }
}

extern "C" void kernel_launch(void* const* d_in, const int* in_sizes, int n_in,
                              void* d_out, int out_size, void* d_ws, size_t ws_size,
                              hipStream_t stream) {
    const float* x      = (const float*)d_in[0];
    const float* a_qr   = (const float*)d_in[1];
    const float* a_kr   = (const float*)d_in[2];
    const float* a_vr   = (const float*)d_in[3];
    const float* a_rtr  = (const float*)d_in[4];
    const float* b_qr   = (const float*)d_in[5];
    const float* b_kr   = (const float*)d_in[6];
    const float* b_vr   = (const float*)d_in[7];
    /* f_ar = d_in[8] unused (dead gelu branch) */
    const float* f_br   = (const float*)d_in[9];
    const float* a_qi   = (const float*)d_in[10];
    const float* a_ki   = (const float*)d_in[11];
    const float* a_vi   = (const float*)d_in[12];
    const float* a_rti  = (const float*)d_in[13];
    const float* b_qi   = (const float*)d_in[14];
    const float* b_ki   = (const float*)d_in[15];
    const float* b_vi   = (const float*)d_in[16];
    /* f_ai = d_in[17] unused */
    const float* f_bi   = (const float*)d_in[18];
    /* f_bias = d_in[19] unused (dead gelu branch) */
    const float* dyta_alpha = (const float*)d_in[20];
    const float* dyta_w     = (const float*)d_in[21];
    const float* dyta_b     = (const float*)d_in[22];
    const float* dytb_alpha = (const float*)d_in[23];
    const float* dytb_w     = (const float*)d_in[24];
    const float* dytb_b     = (const float*)d_in[25];
    const float* dytf_alpha = (const float*)d_in[26];
    const float* dytf_w     = (const float*)d_in[27];
    const float* dytf_b     = (const float*)d_in[28];
    (void)in_sizes; (void)n_in; (void)out_size; (void)ws_size;

    char* ws = (char*)d_ws;
    const size_t MB = 1024 * 1024;
    half2v* xfH = (half2v*)(ws + 0 * MB);           // 16MB packed fp16 complex
    _Float16* x1 = (_Float16*)(ws + 32 * MB);       // 8MB fp16 (R27)
    unsigned short* qb = (unsigned short*)(ws + 48 * MB);  // 8MB
    unsigned short* kb = (unsigned short*)(ws + 56 * MB);  // 8MB
    unsigned short* vb = (unsigned short*)(ws + 64 * MB);  // 8MB
    unsigned short* vT = (unsigned short*)(ws + 72 * MB);  // 8MB
    _Float16* scores   = (_Float16*)(ws + 0 * MB);  // 32MB, overlays dead xfH
    unsigned short* Pb = (unsigned short*)(ws + 0 * MB);   // bf16 P, in place over scores
    _Float16* attnP    = (_Float16*)(ws + 81 * MB); // 16MB: two 8MB fp16 K-split partials
    float* outp = (float*)d_out;

    k1_dyt_fftd<<<2048, 256, 0, stream>>>(x, dyta_alpha, dyta_w, dyta_b, xfH);
    k2_sfft<<<1024, 512, 0, stream>>>(xfH, a_qr, a_qi, a_kr, a_ki, a_vr, a_vi, a_rtr, a_rti);
    k3_mid<<<1024, 256, 0, stream>>>(xfH, x, dytb_alpha, dytb_w, dytb_b,
                                     b_qr, b_qi, b_kr, b_ki, b_vr, b_vi, x1, qb, kb, vb);
    gemm_bt<<<1024, 256, 0, stream>>>(qb, kb, scores, 2048, 2048, 512, 512,
                                      0.04419417382415922f, 1);
    sm_tr<<<9216, 256, 0, stream>>>(scores, Pb, vb, vT);
    gemm_bt<<<dim3(256, 2), 256, 0, stream>>>(Pb, vT, attnP, 2048, 512, 2048, 1024,
                                              1.0f, 1);
    k5_ffn<<<1024, 256, 0, stream>>>(attnP, attnP + (size_t)4 * 2048 * 512, x1,
                                     dytf_alpha, dytf_w, dytf_b, f_br, f_bi, outp);
}